// Round 1
// baseline (243.759 us; speedup 1.0000x reference)
//
#include <hip/hip_runtime.h>

// Fused attention block for MI355X (gfx950).
// Pipeline: conv(x,W) -> GEMM1(qkv) -> postproc(RMS/RoPE/shift/gates, vT) ->
//           windowed flash attention -> GEMM2 -> d_out (f32)

#define TSEQ 8192
#define DIMM 1024
#define NHEAD 8
#define HD 128
#define ATTN_SCALE 0.1f
#define RMS_EPS 1.1920929e-07f

typedef __bf16 bfx2 __attribute__((ext_vector_type(2)));
typedef __bf16 bfx4 __attribute__((ext_vector_type(4)));
typedef __bf16 bfx8 __attribute__((ext_vector_type(8)));
typedef float f32x4 __attribute__((ext_vector_type(4)));

#define GLDS16(g, l)                                                         \
  __builtin_amdgcn_global_load_lds(                                          \
      (const __attribute__((address_space(1))) void*)(g),                    \
      (__attribute__((address_space(3))) void*)(l), 16, 0, 0)

__device__ __forceinline__ float sig_(float z) { return 1.0f / (1.0f + __expf(-z)); }

__device__ __forceinline__ int segof_(int t, const int* __restrict__ sl, int ns) {
  int c = 0;
  for (int i = 0; i < ns; i++) c += (sl[i] <= t);
  return c;
}

// ---------------- f32 -> bf16 conversions ----------------
__global__ void k_conv_x(const float4* __restrict__ x, bfx4* __restrict__ xb, int n4) {
  int i = blockIdx.x * blockDim.x + threadIdx.x;
  int stride = gridDim.x * blockDim.x;
  for (; i < n4; i += stride) {
    float4 v = x[i];
    bfx4 o;
    o[0] = (__bf16)v.x; o[1] = (__bf16)v.y; o[2] = (__bf16)v.z; o[3] = (__bf16)v.w;
    xb[i] = o;
  }
}

// qkvo_w is [4096,1024]; rows <3072 scaled by lam[0] -> w1b, rest by lam[1] -> w2b
__global__ void k_conv_w(const float4* __restrict__ w, const float* __restrict__ lam,
                         bfx4* __restrict__ w1b, bfx4* __restrict__ w2b) {
  const int n4 = 4096 * 1024 / 4;
  const float l0 = lam[0], l1 = lam[1];
  int i = blockIdx.x * blockDim.x + threadIdx.x;
  int stride = gridDim.x * blockDim.x;
  for (; i < n4; i += stride) {
    int row = (i * 4) >> 10;
    float s = (row < 3 * DIMM) ? l0 : l1;
    float4 v = w[i];
    bfx4 o;
    o[0] = (__bf16)(s * v.x); o[1] = (__bf16)(s * v.y);
    o[2] = (__bf16)(s * v.z); o[3] = (__bf16)(s * v.w);
    if (row < 3 * DIMM) w1b[i] = o;
    else                w2b[i - 3 * DIMM * DIMM / 4] = o;
  }
}

// ---------------- GEMM: C[M,N] = A[M,K] * B[N,K]^T (bf16 in, CT out) ----------------
// 128x128 tile, BK=32, 4 waves (2x2 of 64x64), mfma_f32_16x16x32_bf16.
template <typename CT>
__global__ __launch_bounds__(256) void k_gemm_bt(const __bf16* __restrict__ A,
                                                 const __bf16* __restrict__ B,
                                                 CT* __restrict__ C, int M, int N, int K) {
  __shared__ __bf16 As[128][32];
  __shared__ __bf16 Bs[128][32];
  const int tid = threadIdx.x;
  const int wave = tid >> 6, lane = tid & 63;
  const int bm = blockIdx.x, bn = blockIdx.y;
  const int wr = wave >> 1, wc = wave & 1;
  const int lr = lane & 15, ko = (lane >> 4) * 8;

  f32x4 acc[4][4] = {};

  // staging segments: 512 x 16B per tile; wave handles segs [wave*128, wave*128+128)
  const int s0 = wave * 128 + lane;
  const int r0 = s0 >> 2, c0 = (s0 & 3) * 8;
  const int s1 = s0 + 64;
  const int r1 = s1 >> 2, c1 = (s1 & 3) * 8;
  const __bf16* Abase = A + (size_t)(bm * 128) * K;
  const __bf16* Bbase = B + (size_t)(bn * 128) * K;
  __bf16* AsB = &As[0][0];
  __bf16* BsB = &Bs[0][0];

  for (int kt = 0; kt < K; kt += 32) {
    GLDS16(Abase + (size_t)r0 * K + kt + c0, AsB + wave * 1024);
    GLDS16(Abase + (size_t)r1 * K + kt + c1, AsB + wave * 1024 + 512);
    GLDS16(Bbase + (size_t)r0 * K + kt + c0, BsB + wave * 1024);
    GLDS16(Bbase + (size_t)r1 * K + kt + c1, BsB + wave * 1024 + 512);
    __syncthreads();
    bfx8 af[4], bfr[4];
#pragma unroll
    for (int m = 0; m < 4; m++) af[m] = *(const bfx8*)&As[wr * 64 + m * 16 + lr][ko];
#pragma unroll
    for (int n = 0; n < 4; n++) bfr[n] = *(const bfx8*)&Bs[wc * 64 + n * 16 + lr][ko];
#pragma unroll
    for (int m = 0; m < 4; m++)
#pragma unroll
      for (int n = 0; n < 4; n++)
        acc[m][n] = __builtin_amdgcn_mfma_f32_16x16x32_bf16(af[m], bfr[n], acc[m][n], 0, 0, 0);
    __syncthreads();
  }

  // C/D layout: col = lane&15, row = (lane>>4)*4 + reg
  const int rbase = bm * 128 + wr * 64 + (lane >> 4) * 4;
  const int cbase = bn * 128 + wc * 64 + lr;
#pragma unroll
  for (int m = 0; m < 4; m++)
#pragma unroll
    for (int rr = 0; rr < 4; rr++) {
      size_t rowoff = (size_t)(rbase + m * 16 + rr) * N + cbase;
#pragma unroll
      for (int n = 0; n < 4; n++) C[rowoff + n * 16] = (CT)acc[m][n][rr];
    }
}

// ---------------- postprocess: RMS, RoPE, key-offset, gates, vT ----------------
// one block = one token; 8 waves = 8 heads; lane handles dims (2l, 2l+1)
__global__ __launch_bounds__(512) void k_postproc(
    const __bf16* __restrict__ qkv, const float* __restrict__ x,
    const float* __restrict__ ve, const float* __restrict__ f1,
    const float* __restrict__ f2, const float* __restrict__ agw,
    const float* __restrict__ vgw, const int* __restrict__ koff_p,
    __bf16* __restrict__ qb, __bf16* __restrict__ kb,
    __bf16* __restrict__ vT, float* __restrict__ ag) {
  const int t = blockIdx.x;
  const int h = threadIdx.x >> 6;
  const int l = threadIdx.x & 63;
  const int d0 = 2 * l, d1 = 2 * l + 1;
  const size_t qoff = (size_t)t * (3 * DIMM) + h * HD;

  bfx2 qv = *(const bfx2*)&qkv[qoff + d0];
  bfx2 kv = *(const bfx2*)&qkv[qoff + DIMM + d0];
  bfx2 vv = *(const bfx2*)&qkv[qoff + 2 * DIMM + d0];
  float q0 = (float)qv[0], q1 = (float)qv[1];
  float k0 = (float)kv[0], k1 = (float)kv[1];
  float v0 = (float)vv[0], v1 = (float)vv[1];

  // RMS norm over 128 dims (64-lane butterfly)
  float sq = q0 * q0 + q1 * q1;
  float sk = k0 * k0 + k1 * k1;
#pragma unroll
  for (int off = 32; off; off >>= 1) {
    sq += __shfl_xor(sq, off);
    sk += __shfl_xor(sk, off);
  }
  float rq = rsqrtf(sq * (1.0f / 128.0f) + RMS_EPS);
  float rk = rsqrtf(sk * (1.0f / 128.0f) + RMS_EPS);
  q0 *= rq; q1 *= rq; k0 *= rk; k1 *= rk;

  // RoPE: rot[2i] = c*x[2i] + s2*x[2i+1]; rot[2i+1] = c1*x[2i+1] + s1*x[2i]
  float c0 = f1[(size_t)t * HD + d0], c1 = f1[(size_t)t * HD + d1];
  float s0 = f2[(size_t)t * HD + d0], s1 = f2[(size_t)t * HD + d1];
  float rq0 = c0 * q0 + s0 * q1, rq1 = c1 * q1 + s1 * q0;
  float rk0 = c0 * k0 + s0 * k1, rk1 = c1 * k1 + s1 * k0;

  bfx2 qo; qo[0] = (__bf16)rq0; qo[1] = (__bf16)rq1;
  *(bfx2*)&qb[(size_t)t * DIMM + h * HD + d0] = qo;

  // key offset: hi half (d>=64) shifted to t+1 (t==0 also keeps its own)
  bfx2 ko2; ko2[0] = (__bf16)rk0; ko2[1] = (__bf16)rk1;
  const int koff = *koff_p;
  const size_t kcol = (size_t)h * HD + d0;
  if (!koff || l < 32) {
    *(bfx2*)&kb[(size_t)t * DIMM + kcol] = ko2;
  } else {
    if (t + 1 < TSEQ) *(bfx2*)&kb[(size_t)(t + 1) * DIMM + kcol] = ko2;
    if (t == 0)       *(bfx2*)&kb[kcol] = ko2;
  }

  // gates from x[t, :12]
  float zg = 0.0f, za = 0.0f;
#pragma unroll
  for (int j = 0; j < 12; j++) {
    float xv = x[(size_t)t * DIMM + j];
    zg += xv * vgw[h * 12 + j];
    za += xv * agw[h * 12 + j];
  }
  float gv = 2.0f * sig_(zg);
  v0 += gv * ve[(size_t)t * DIMM + h * HD + d0];
  v1 += gv * ve[(size_t)t * DIMM + h * HD + d1];
  // V transposed: vT[h*128+d][t]
  vT[(size_t)(h * HD + d0) * TSEQ + t] = (__bf16)v0;
  vT[(size_t)(h * HD + d1) * TSEQ + t] = (__bf16)v1;

  if (l == 0) ag[(size_t)t * NHEAD + h] = sig_(za);
}

// ---------------- windowed varlen flash attention ----------------
// grid (64 qblocks, 8 heads); 4 waves, wave w owns rows [w*32, w*32+32)
__global__ __launch_bounds__(256) void k_attn(
    const __bf16* __restrict__ qb, const __bf16* __restrict__ kb,
    const __bf16* __restrict__ vT, const float* __restrict__ ag,
    const int* __restrict__ sl, int ns, __bf16* __restrict__ yb) {
  __shared__ __bf16 p_lds[4][32][64];
  const int n = blockIdx.x, h = blockIdx.y;
  const int w = threadIdx.x >> 6, l = threadIdx.x & 63;
  const int lr = l & 15, lg = l >> 4;
  const int ko = lg * 8;
  const int q0r = n * 128 + w * 32;

  // Q fragments: [rowfrag m][kstep s]
  bfx8 qf[2][4];
#pragma unroll
  for (int m = 0; m < 2; m++)
#pragma unroll
    for (int s = 0; s < 4; s++)
      qf[m][s] = *(const bfx8*)&qb[(size_t)(q0r + m * 16 + lr) * DIMM + h * HD + s * 32 + ko];

  int segq[2][4];
#pragma unroll
  for (int m = 0; m < 2; m++)
#pragma unroll
    for (int rr = 0; rr < 4; rr++)
      segq[m][rr] = segof_(q0r + m * 16 + lg * 4 + rr, sl, ns);

  f32x4 o[2][8] = {};
  float mr[2][4], lsum[2][4];
#pragma unroll
  for (int m = 0; m < 2; m++)
#pragma unroll
    for (int rr = 0; rr < 4; rr++) { mr[m][rr] = -1e30f; lsum[m][rr] = 0.0f; }

  for (int kbk = 0; kbk < 4; kbk++) {
    if (n == 0 && kbk < 2) continue;  // keys from zero-padding region, always masked
    const int kbase = kbk * 64;

    // S = Q K^T for 64 keys
    f32x4 sf[2][4] = {};
#pragma unroll
    for (int s = 0; s < 4; s++) {
#pragma unroll
      for (int kf = 0; kf < 4; kf++) {
        int key = n * 128 - 128 + kbase + kf * 16 + lr;
        bfx8 bfr = *(const bfx8*)&kb[(size_t)key * DIMM + h * HD + s * 32 + ko];
#pragma unroll
        for (int m = 0; m < 2; m++)
          sf[m][kf] = __builtin_amdgcn_mfma_f32_16x16x32_bf16(qf[m][s], bfr, sf[m][kf], 0, 0, 0);
      }
    }

    // mask + scale
    int gk[4], segk[4];
#pragma unroll
    for (int kf = 0; kf < 4; kf++) {
      gk[kf] = n * 128 - 128 + kbase + kf * 16 + lr;
      segk[kf] = (gk[kf] >= 0) ? segof_(gk[kf], sl, ns) : -1;
    }
#pragma unroll
    for (int m = 0; m < 2; m++)
#pragma unroll
      for (int rr = 0; rr < 4; rr++) {
        int row = w * 32 + m * 16 + lg * 4 + rr;
#pragma unroll
        for (int kf = 0; kf < 4; kf++) {
          int ki = kbase + kf * 16 + lr;
          bool valid = (gk[kf] >= 0) && (ki >= row) && (ki <= row + 128) &&
                       (segk[kf] == segq[m][rr]);
          float sv = sf[m][kf][rr];
          sf[m][kf][rr] = valid ? sv * ATTN_SCALE : -1e30f;
        }
      }

    // online softmax (row stats replicated across the 16 lanes of a row group)
#pragma unroll
    for (int m = 0; m < 2; m++)
#pragma unroll
      for (int rr = 0; rr < 4; rr++) {
        float mx = fmaxf(fmaxf(sf[m][0][rr], sf[m][1][rr]), fmaxf(sf[m][2][rr], sf[m][3][rr]));
#pragma unroll
        for (int off = 8; off; off >>= 1) mx = fmaxf(mx, __shfl_xor(mx, off));
        float mnew = fmaxf(mr[m][rr], mx);
        float corr = __expf(mr[m][rr] - mnew);
        float ls = 0.0f;
#pragma unroll
        for (int kf = 0; kf < 4; kf++) {
          float sv = sf[m][kf][rr];
          float p = (sv <= -1e29f) ? 0.0f : __expf(sv - mnew);
          sf[m][kf][rr] = p;
          ls += p;
        }
#pragma unroll
        for (int off = 8; off; off >>= 1) ls += __shfl_xor(ls, off);
        lsum[m][rr] = lsum[m][rr] * corr + ls;
        mr[m][rr] = mnew;
#pragma unroll
        for (int nf = 0; nf < 8; nf++) o[m][nf][rr] *= corr;
      }

    // P -> LDS (transpose C-layout -> A-layout); same-wave, no barrier needed
#pragma unroll
    for (int m = 0; m < 2; m++)
#pragma unroll
      for (int kf = 0; kf < 4; kf++)
#pragma unroll
        for (int rr = 0; rr < 4; rr++)
          p_lds[w][m * 16 + lg * 4 + rr][kf * 16 + lr] = (__bf16)sf[m][kf][rr];

    // O += P V
#pragma unroll
    for (int s2 = 0; s2 < 2; s2++) {
      bfx8 af[2];
#pragma unroll
      for (int m = 0; m < 2; m++) af[m] = *(const bfx8*)&p_lds[w][m * 16 + lr][s2 * 32 + ko];
      int keyg = n * 128 - 128 + kbase + s2 * 32 + ko;
#pragma unroll
      for (int nf = 0; nf < 8; nf++) {
        bfx8 bfr = *(const bfx8*)&vT[(size_t)(h * HD + nf * 16 + lr) * TSEQ + keyg];
#pragma unroll
        for (int m = 0; m < 2; m++)
          o[m][nf] = __builtin_amdgcn_mfma_f32_16x16x32_bf16(af[m], bfr, o[m][nf], 0, 0, 0);
      }
    }
  }

  // epilogue: normalize, gate, store
#pragma unroll
  for (int m = 0; m < 2; m++)
#pragma unroll
    for (int rr = 0; rr < 4; rr++) {
      int gq = q0r + m * 16 + lg * 4 + rr;
      float sc = (1.0f / lsum[m][rr]) * ag[(size_t)gq * NHEAD + h];
#pragma unroll
      for (int nf = 0; nf < 8; nf++)
        yb[(size_t)gq * DIMM + h * HD + nf * 16 + lr] = (__bf16)(o[m][nf][rr] * sc);
    }
}

// ---------------- launch ----------------
extern "C" void kernel_launch(void* const* d_in, const int* in_sizes, int n_in,
                              void* d_out, int out_size, void* d_ws, size_t ws_size,
                              hipStream_t stream) {
  const float* x   = (const float*)d_in[0];
  const float* qw  = (const float*)d_in[1];
  const float* ve  = (const float*)d_in[2];
  const float* lam = (const float*)d_in[3];
  const float* f1  = (const float*)d_in[4];
  const float* f2  = (const float*)d_in[5];
  const float* agw = (const float*)d_in[6];
  const float* vgw = (const float*)d_in[7];
  const int*   sl  = (const int*)d_in[8];
  const int    ns  = in_sizes[8];
  const int*   koff = (const int*)d_in[10];
  float* out = (float*)d_out;
  char* ws = (char*)d_ws;

  // workspace layout (bytes):
  // [0,16M)   xb (bf16 x)            -- later aliased by vT
  // [16M,22M) w1b  [22M,24M) w2b
  // [24M,72M) qkvb (bf16 qkv)        -- first 16M later aliased by ybuf
  // [72M,88M) qbuf  [88M,104M) kbuf
  // [104M, +256K) attn gate (f32)
  const size_t MB = 1024 * 1024;
  if (ws_size < 105 * MB) return;  // loud failure: out stays zero
  __bf16* xb   = (__bf16*)(ws);
  __bf16* w1b  = (__bf16*)(ws + 16 * MB);
  __bf16* w2b  = (__bf16*)(ws + 22 * MB);
  __bf16* qkvb = (__bf16*)(ws + 24 * MB);
  __bf16* qbuf = (__bf16*)(ws + 72 * MB);
  __bf16* kbuf = (__bf16*)(ws + 88 * MB);
  float*  ag   = (float*)(ws + 104 * MB);
  __bf16* vT   = xb;    // xb dead after GEMM1
  __bf16* ybuf = qkvb;  // qkvb dead after postproc

  k_conv_x<<<2048, 256, 0, stream>>>((const float4*)x, (bfx4*)xb, TSEQ * DIMM / 4);
  k_conv_w<<<1024, 256, 0, stream>>>((const float4*)qw, lam, (bfx4*)w1b, (bfx4*)w2b);
  k_gemm_bt<__bf16><<<dim3(TSEQ / 128, 3 * DIMM / 128), 256, 0, stream>>>(
      xb, w1b, qkvb, TSEQ, 3 * DIMM, DIMM);
  k_postproc<<<TSEQ, 512, 0, stream>>>(qkvb, x, ve, f1, f2, agw, vgw, koff,
                                       qbuf, kbuf, vT, ag);
  k_attn<<<dim3(TSEQ / 128, NHEAD), 256, 0, stream>>>(qbuf, kbuf, vT, ag, sl, ns, ybuf);
  k_gemm_bt<float><<<dim3(TSEQ / 128, DIMM / 128), 256, 0, stream>>>(
      ybuf, w2b, out, TSEQ, DIMM, DIMM);
}

// Round 2
// 213.882 us; speedup vs baseline: 1.1397x; 1.1397x over previous
//
#include <hip/hip_runtime.h>

// Fused attention block for MI355X (gfx950).
// Pipeline: conv(x,W) -> GEMM1(qkv) -> k_qk(RMS/RoPE/shift) + k_vgate(gates,vT) ->
//           windowed flash attention -> GEMM2 -> d_out (f32)

#define TSEQ 8192
#define DIMM 1024
#define NHEAD 8
#define HD 128
#define ATTN_SCALE 0.1f
#define RMS_EPS 1.1920929e-07f

typedef __bf16 bfx2 __attribute__((ext_vector_type(2)));
typedef __bf16 bfx4 __attribute__((ext_vector_type(4)));
typedef __bf16 bfx8 __attribute__((ext_vector_type(8)));
typedef float f32x4 __attribute__((ext_vector_type(4)));

#define GLDS16(g, l)                                                         \
  __builtin_amdgcn_global_load_lds(                                          \
      (const __attribute__((address_space(1))) void*)(g),                    \
      (__attribute__((address_space(3))) void*)(l), 16, 0, 0)

__device__ __forceinline__ float sig_(float z) { return 1.0f / (1.0f + __expf(-z)); }

__device__ __forceinline__ int segof_(int t, const int* __restrict__ sl, int ns) {
  int c = 0;
  for (int i = 0; i < ns; i++) c += (sl[i] <= t);
  return c;
}

// ---------------- f32 -> bf16 conversions ----------------
__global__ void k_conv_x(const float4* __restrict__ x, bfx4* __restrict__ xb, int n4) {
  int i = blockIdx.x * blockDim.x + threadIdx.x;
  int stride = gridDim.x * blockDim.x;
  for (; i < n4; i += stride) {
    float4 v = x[i];
    bfx4 o;
    o[0] = (__bf16)v.x; o[1] = (__bf16)v.y; o[2] = (__bf16)v.z; o[3] = (__bf16)v.w;
    xb[i] = o;
  }
}

// qkvo_w is [4096,1024]; rows <3072 scaled by lam[0] -> w1b, rest by lam[1] -> w2b
__global__ void k_conv_w(const float4* __restrict__ w, const float* __restrict__ lam,
                         bfx4* __restrict__ w1b, bfx4* __restrict__ w2b) {
  const int n4 = 4096 * 1024 / 4;
  const float l0 = lam[0], l1 = lam[1];
  int i = blockIdx.x * blockDim.x + threadIdx.x;
  int stride = gridDim.x * blockDim.x;
  for (; i < n4; i += stride) {
    int row = (i * 4) >> 10;
    float s = (row < 3 * DIMM) ? l0 : l1;
    float4 v = w[i];
    bfx4 o;
    o[0] = (__bf16)(s * v.x); o[1] = (__bf16)(s * v.y);
    o[2] = (__bf16)(s * v.z); o[3] = (__bf16)(s * v.w);
    if (row < 3 * DIMM) w1b[i] = o;
    else                w2b[i - 3 * DIMM * DIMM / 4] = o;
  }
}

// ---------------- GEMM: C[M,N] = A[M,K] * B[N,K]^T (bf16 in, CT out) ----------------
// 128x128 tile, BK=32, 4 waves (2x2 of 64x64), mfma_f32_16x16x32_bf16.
template <typename CT>
__global__ __launch_bounds__(256) void k_gemm_bt(const __bf16* __restrict__ A,
                                                 const __bf16* __restrict__ B,
                                                 CT* __restrict__ C, int M, int N, int K) {
  __shared__ __bf16 As[128][32];
  __shared__ __bf16 Bs[128][32];
  const int tid = threadIdx.x;
  const int wave = tid >> 6, lane = tid & 63;
  const int bm = blockIdx.x, bn = blockIdx.y;
  const int wr = wave >> 1, wc = wave & 1;
  const int lr = lane & 15, ko = (lane >> 4) * 8;

  f32x4 acc[4][4] = {};

  const int s0 = wave * 128 + lane;
  const int r0 = s0 >> 2, c0 = (s0 & 3) * 8;
  const int s1 = s0 + 64;
  const int r1 = s1 >> 2, c1 = (s1 & 3) * 8;
  const __bf16* Abase = A + (size_t)(bm * 128) * K;
  const __bf16* Bbase = B + (size_t)(bn * 128) * K;
  __bf16* AsB = &As[0][0];
  __bf16* BsB = &Bs[0][0];

  for (int kt = 0; kt < K; kt += 32) {
    GLDS16(Abase + (size_t)r0 * K + kt + c0, AsB + wave * 1024);
    GLDS16(Abase + (size_t)r1 * K + kt + c1, AsB + wave * 1024 + 512);
    GLDS16(Bbase + (size_t)r0 * K + kt + c0, BsB + wave * 1024);
    GLDS16(Bbase + (size_t)r1 * K + kt + c1, BsB + wave * 1024 + 512);
    __syncthreads();
    bfx8 af[4], bfr[4];
#pragma unroll
    for (int m = 0; m < 4; m++) af[m] = *(const bfx8*)&As[wr * 64 + m * 16 + lr][ko];
#pragma unroll
    for (int n = 0; n < 4; n++) bfr[n] = *(const bfx8*)&Bs[wc * 64 + n * 16 + lr][ko];
#pragma unroll
    for (int m = 0; m < 4; m++)
#pragma unroll
      for (int n = 0; n < 4; n++)
        acc[m][n] = __builtin_amdgcn_mfma_f32_16x16x32_bf16(af[m], bfr[n], acc[m][n], 0, 0, 0);
    __syncthreads();
  }

  const int rbase = bm * 128 + wr * 64 + (lane >> 4) * 4;
  const int cbase = bn * 128 + wc * 64 + lr;
#pragma unroll
  for (int m = 0; m < 4; m++)
#pragma unroll
    for (int rr = 0; rr < 4; rr++) {
      size_t rowoff = (size_t)(rbase + m * 16 + rr) * N + cbase;
#pragma unroll
      for (int n = 0; n < 4; n++) C[rowoff + n * 16] = (CT)acc[m][n][rr];
    }
}

// ---------------- q/k postprocess: RMS, RoPE, key-offset ----------------
// one block = one token; 8 waves = 8 heads; lane handles dims (2l, 2l+1)
__global__ __launch_bounds__(512) void k_qk(
    const __bf16* __restrict__ qkv, const float* __restrict__ f1,
    const float* __restrict__ f2, const int* __restrict__ koff_p,
    __bf16* __restrict__ qb, __bf16* __restrict__ kb) {
  const int t = blockIdx.x;
  const int h = threadIdx.x >> 6;
  const int l = threadIdx.x & 63;
  const int d0 = 2 * l, d1 = 2 * l + 1;
  const size_t qoff = (size_t)t * (3 * DIMM) + h * HD;

  bfx2 qv = *(const bfx2*)&qkv[qoff + d0];
  bfx2 kv = *(const bfx2*)&qkv[qoff + DIMM + d0];
  float q0 = (float)qv[0], q1 = (float)qv[1];
  float k0 = (float)kv[0], k1 = (float)kv[1];

  // RMS norm over 128 dims (64-lane butterfly)
  float sq = q0 * q0 + q1 * q1;
  float sk = k0 * k0 + k1 * k1;
#pragma unroll
  for (int off = 32; off; off >>= 1) {
    sq += __shfl_xor(sq, off);
    sk += __shfl_xor(sk, off);
  }
  float rq = rsqrtf(sq * (1.0f / 128.0f) + RMS_EPS);
  float rk = rsqrtf(sk * (1.0f / 128.0f) + RMS_EPS);
  q0 *= rq; q1 *= rq; k0 *= rk; k1 *= rk;

  // RoPE
  float2 cc = *(const float2*)&f1[(size_t)t * HD + d0];
  float2 ss = *(const float2*)&f2[(size_t)t * HD + d0];
  float rq0 = cc.x * q0 + ss.x * q1, rq1 = cc.y * q1 + ss.y * q0;
  float rk0 = cc.x * k0 + ss.x * k1, rk1 = cc.y * k1 + ss.y * k0;

  bfx2 qo; qo[0] = (__bf16)rq0; qo[1] = (__bf16)rq1;
  *(bfx2*)&qb[(size_t)t * DIMM + h * HD + d0] = qo;

  // key offset: hi half (d>=64) shifted to t+1 (t==0 also keeps its own)
  bfx2 ko2; ko2[0] = (__bf16)rk0; ko2[1] = (__bf16)rk1;
  const int koff = *koff_p;
  const size_t kcol = (size_t)h * HD + d0;
  if (!koff || l < 32) {
    *(bfx2*)&kb[(size_t)t * DIMM + kcol] = ko2;
  } else {
    if (t + 1 < TSEQ) *(bfx2*)&kb[(size_t)(t + 1) * DIMM + kcol] = ko2;
    if (t == 0)       *(bfx2*)&kb[kcol] = ko2;
  }
}

// ---------------- v postprocess: gates + ve-gate + LDS-tiled transpose ----------------
// grid (TSEQ/64, 2); block handles 64 tokens x 4 heads. vT[h*128+d][t], coalesced.
__global__ __launch_bounds__(512) void k_vgate(
    const __bf16* __restrict__ qkv, const float* __restrict__ x,
    const float* __restrict__ ve, const float* __restrict__ agw,
    const float* __restrict__ vgw, __bf16* __restrict__ vT,
    float* __restrict__ ag) {
  __shared__ float vg_lds[64][4];
  __shared__ __bf16 vtile[HD][68];  // stride 68 elems = 136B: 8B-aligned rows, <=2-way banks
  const int t0 = blockIdx.x * 64;
  const int hbase = blockIdx.y * 4;
  const int tid = threadIdx.x;

  // phase 1: gates (one (token, head) pair per thread; tid<256 active)
  if (tid < 256) {
    const int tl = tid >> 2, hh = tid & 3;
    const int h = hbase + hh;
    const int t = t0 + tl;
    float za = 0.0f, zg = 0.0f;
#pragma unroll
    for (int j = 0; j < 12; j++) {
      float xv = x[(size_t)t * DIMM + j];
      za += xv * agw[h * 12 + j];
      zg += xv * vgw[h * 12 + j];
    }
    ag[(size_t)t * NHEAD + h] = sig_(za);
    vg_lds[tl][hh] = 2.0f * sig_(zg);
  }
  __syncthreads();

  const int w = tid >> 6, l = tid & 63;
  const int dout = tid >> 2, tof = (tid & 3) * 16;
  for (int hh = 0; hh < 4; hh++) {
    const int h = hbase + hh;
    // fill vtile[d][t_local]; lane l owns dims l and l+64 (2-way LDS bank alias = free)
#pragma unroll
    for (int it = 0; it < 8; it++) {
      const int tl = w * 8 + it;
      const int t = t0 + tl;
      const size_t voff = (size_t)t * (3 * DIMM) + 2 * DIMM + h * HD;
      float va = (float)qkv[voff + l];
      float vb = (float)qkv[voff + l + 64];
      float vea = ve[(size_t)t * DIMM + h * HD + l];
      float veb = ve[(size_t)t * DIMM + h * HD + l + 64];
      float gv = vg_lds[tl][hh];
      vtile[l][tl]      = (__bf16)(va + gv * vea);
      vtile[l + 64][tl] = (__bf16)(vb + gv * veb);
    }
    __syncthreads();
    // write out: thread covers vT row (h*128+dout), tokens [t0+tof, t0+tof+16)
    {
      bfx4 a0 = *(const bfx4*)&vtile[dout][tof];
      bfx4 a1 = *(const bfx4*)&vtile[dout][tof + 4];
      bfx4 a2 = *(const bfx4*)&vtile[dout][tof + 8];
      bfx4 a3 = *(const bfx4*)&vtile[dout][tof + 12];
      bfx8 p0, p1;
      p0[0]=a0[0]; p0[1]=a0[1]; p0[2]=a0[2]; p0[3]=a0[3];
      p0[4]=a1[0]; p0[5]=a1[1]; p0[6]=a1[2]; p0[7]=a1[3];
      p1[0]=a2[0]; p1[1]=a2[1]; p1[2]=a2[2]; p1[3]=a2[3];
      p1[4]=a3[0]; p1[5]=a3[1]; p1[6]=a3[2]; p1[7]=a3[3];
      __bf16* dst = &vT[(size_t)(h * HD + dout) * TSEQ + t0 + tof];
      *(bfx8*)dst = p0;
      *(bfx8*)(dst + 8) = p1;
    }
    __syncthreads();
  }
}

// ---------------- windowed varlen flash attention ----------------
// grid (64 qblocks, 8 heads); 4 waves, wave w owns rows [w*32, w*32+32)
__global__ __launch_bounds__(256) void k_attn(
    const __bf16* __restrict__ qb, const __bf16* __restrict__ kb,
    const __bf16* __restrict__ vT, const float* __restrict__ ag,
    const int* __restrict__ sl, int ns, __bf16* __restrict__ yb) {
  __shared__ __bf16 p_lds[4][32][64];
  const int n = blockIdx.x, h = blockIdx.y;
  const int w = threadIdx.x >> 6, l = threadIdx.x & 63;
  const int lr = l & 15, lg = l >> 4;
  const int ko = lg * 8;
  const int q0r = n * 128 + w * 32;

  bfx8 qf[2][4];
#pragma unroll
  for (int m = 0; m < 2; m++)
#pragma unroll
    for (int s = 0; s < 4; s++)
      qf[m][s] = *(const bfx8*)&qb[(size_t)(q0r + m * 16 + lr) * DIMM + h * HD + s * 32 + ko];

  int segq[2][4];
#pragma unroll
  for (int m = 0; m < 2; m++)
#pragma unroll
    for (int rr = 0; rr < 4; rr++)
      segq[m][rr] = segof_(q0r + m * 16 + lg * 4 + rr, sl, ns);

  f32x4 o[2][8] = {};
  float mr[2][4], lsum[2][4];
#pragma unroll
  for (int m = 0; m < 2; m++)
#pragma unroll
    for (int rr = 0; rr < 4; rr++) { mr[m][rr] = -1e30f; lsum[m][rr] = 0.0f; }

  for (int kbk = 0; kbk < 4; kbk++) {
    if (n == 0 && kbk < 2) continue;
    const int kbase = kbk * 64;

    f32x4 sf[2][4] = {};
#pragma unroll
    for (int s = 0; s < 4; s++) {
#pragma unroll
      for (int kf = 0; kf < 4; kf++) {
        int key = n * 128 - 128 + kbase + kf * 16 + lr;
        bfx8 bfr = *(const bfx8*)&kb[(size_t)key * DIMM + h * HD + s * 32 + ko];
#pragma unroll
        for (int m = 0; m < 2; m++)
          sf[m][kf] = __builtin_amdgcn_mfma_f32_16x16x32_bf16(qf[m][s], bfr, sf[m][kf], 0, 0, 0);
      }
    }

    int gk[4], segk[4];
#pragma unroll
    for (int kf = 0; kf < 4; kf++) {
      gk[kf] = n * 128 - 128 + kbase + kf * 16 + lr;
      segk[kf] = (gk[kf] >= 0) ? segof_(gk[kf], sl, ns) : -1;
    }
#pragma unroll
    for (int m = 0; m < 2; m++)
#pragma unroll
      for (int rr = 0; rr < 4; rr++) {
        int row = w * 32 + m * 16 + lg * 4 + rr;
#pragma unroll
        for (int kf = 0; kf < 4; kf++) {
          int ki = kbase + kf * 16 + lr;
          bool valid = (gk[kf] >= 0) && (ki >= row) && (ki <= row + 128) &&
                       (segk[kf] == segq[m][rr]);
          float sv = sf[m][kf][rr];
          sf[m][kf][rr] = valid ? sv * ATTN_SCALE : -1e30f;
        }
      }

#pragma unroll
    for (int m = 0; m < 2; m++)
#pragma unroll
      for (int rr = 0; rr < 4; rr++) {
        float mx = fmaxf(fmaxf(sf[m][0][rr], sf[m][1][rr]), fmaxf(sf[m][2][rr], sf[m][3][rr]));
#pragma unroll
        for (int off = 8; off; off >>= 1) mx = fmaxf(mx, __shfl_xor(mx, off));
        float mnew = fmaxf(mr[m][rr], mx);
        float corr = __expf(mr[m][rr] - mnew);
        float ls = 0.0f;
#pragma unroll
        for (int kf = 0; kf < 4; kf++) {
          float sv = sf[m][kf][rr];
          float p = (sv <= -1e29f) ? 0.0f : __expf(sv - mnew);
          sf[m][kf][rr] = p;
          ls += p;
        }
#pragma unroll
        for (int off = 8; off; off >>= 1) ls += __shfl_xor(ls, off);
        lsum[m][rr] = lsum[m][rr] * corr + ls;
        mr[m][rr] = mnew;
#pragma unroll
        for (int nf = 0; nf < 8; nf++) o[m][nf][rr] *= corr;
      }

#pragma unroll
    for (int m = 0; m < 2; m++)
#pragma unroll
      for (int kf = 0; kf < 4; kf++)
#pragma unroll
        for (int rr = 0; rr < 4; rr++)
          p_lds[w][m * 16 + lg * 4 + rr][kf * 16 + lr] = (__bf16)sf[m][kf][rr];

#pragma unroll
    for (int s2 = 0; s2 < 2; s2++) {
      bfx8 af[2];
#pragma unroll
      for (int m = 0; m < 2; m++) af[m] = *(const bfx8*)&p_lds[w][m * 16 + lr][s2 * 32 + ko];
      int keyg = n * 128 - 128 + kbase + s2 * 32 + ko;
#pragma unroll
      for (int nf = 0; nf < 8; nf++) {
        bfx8 bfr = *(const bfx8*)&vT[(size_t)(h * HD + nf * 16 + lr) * TSEQ + keyg];
#pragma unroll
        for (int m = 0; m < 2; m++)
          o[m][nf] = __builtin_amdgcn_mfma_f32_16x16x32_bf16(af[m], bfr, o[m][nf], 0, 0, 0);
      }
    }
  }

#pragma unroll
  for (int m = 0; m < 2; m++)
#pragma unroll
    for (int rr = 0; rr < 4; rr++) {
      int gq = q0r + m * 16 + lg * 4 + rr;
      float sc = (1.0f / lsum[m][rr]) * ag[(size_t)gq * NHEAD + h];
#pragma unroll
      for (int nf = 0; nf < 8; nf++)
        yb[(size_t)gq * DIMM + h * HD + nf * 16 + lr] = (__bf16)(o[m][nf][rr] * sc);
    }
}

// ---------------- launch ----------------
extern "C" void kernel_launch(void* const* d_in, const int* in_sizes, int n_in,
                              void* d_out, int out_size, void* d_ws, size_t ws_size,
                              hipStream_t stream) {
  const float* x   = (const float*)d_in[0];
  const float* qw  = (const float*)d_in[1];
  const float* ve  = (const float*)d_in[2];
  const float* lam = (const float*)d_in[3];
  const float* f1  = (const float*)d_in[4];
  const float* f2  = (const float*)d_in[5];
  const float* agw = (const float*)d_in[6];
  const float* vgw = (const float*)d_in[7];
  const int*   sl  = (const int*)d_in[8];
  const int    ns  = in_sizes[8];
  const int*   koff = (const int*)d_in[10];
  float* out = (float*)d_out;
  char* ws = (char*)d_ws;

  // workspace layout (bytes):
  // [0,16M)   xb (bf16 x)            -- later aliased by vT
  // [16M,22M) w1b  [22M,24M) w2b
  // [24M,72M) qkvb (bf16 qkv)        -- first 16M later aliased by ybuf
  // [72M,88M) qbuf  [88M,104M) kbuf
  // [104M, +256K) attn gate (f32)
  const size_t MB = 1024 * 1024;
  if (ws_size < 105 * MB) return;
  __bf16* xb   = (__bf16*)(ws);
  __bf16* w1b  = (__bf16*)(ws + 16 * MB);
  __bf16* w2b  = (__bf16*)(ws + 22 * MB);
  __bf16* qkvb = (__bf16*)(ws + 24 * MB);
  __bf16* qbuf = (__bf16*)(ws + 72 * MB);
  __bf16* kbuf = (__bf16*)(ws + 88 * MB);
  float*  ag   = (float*)(ws + 104 * MB);
  __bf16* vT   = xb;    // xb dead after GEMM1
  __bf16* ybuf = qkvb;  // qkvb dead after k_qk/k_vgate

  k_conv_x<<<2048, 256, 0, stream>>>((const float4*)x, (bfx4*)xb, TSEQ * DIMM / 4);
  k_conv_w<<<1024, 256, 0, stream>>>((const float4*)qw, lam, (bfx4*)w1b, (bfx4*)w2b);
  k_gemm_bt<__bf16><<<dim3(TSEQ / 128, 3 * DIMM / 128), 256, 0, stream>>>(
      xb, w1b, qkvb, TSEQ, 3 * DIMM, DIMM);
  k_qk<<<TSEQ, 512, 0, stream>>>(qkvb, f1, f2, koff, qbuf, kbuf);
  k_vgate<<<dim3(TSEQ / 64, 2), 512, 0, stream>>>(qkvb, x, ve, agw, vgw, vT, ag);
  k_attn<<<dim3(TSEQ / 128, NHEAD), 256, 0, stream>>>(qbuf, kbuf, vT, ag, sl, ns, ybuf);
  k_gemm_bt<float><<<dim3(TSEQ / 128, DIMM / 128), 256, 0, stream>>>(
      ybuf, w2b, out, TSEQ, DIMM, DIMM);
}

// Round 3
// 205.197 us; speedup vs baseline: 1.1879x; 1.0423x over previous
//
#include <hip/hip_runtime.h>

// Fused attention block for MI355X (gfx950).
// Pipeline: conv(x,W) -> GEMM1(qkv) -> k_qk(RMS/RoPE/shift) + k_vgate(gates,vT) ->
//           windowed flash attention -> GEMM2 -> d_out (f32)

#define TSEQ 8192
#define DIMM 1024
#define NHEAD 8
#define HD 128
#define ATTN_SCALE 0.1f
#define RMS_EPS 1.1920929e-07f

typedef __bf16 bfx2 __attribute__((ext_vector_type(2)));
typedef __bf16 bfx4 __attribute__((ext_vector_type(4)));
typedef __bf16 bfx8 __attribute__((ext_vector_type(8)));
typedef float f32x4 __attribute__((ext_vector_type(4)));

#define GLDS16(g, l)                                                         \
  __builtin_amdgcn_global_load_lds(                                          \
      (const __attribute__((address_space(1))) void*)(g),                    \
      (__attribute__((address_space(3))) void*)(l), 16, 0, 0)

__device__ __forceinline__ float sig_(float z) { return 1.0f / (1.0f + __expf(-z)); }

__device__ __forceinline__ int segof_(int t, const int* __restrict__ sl, int ns) {
  int c = 0;
  for (int i = 0; i < ns; i++) c += (sl[i] <= t);
  return c;
}

// ---------------- f32 -> bf16 conversions ----------------
__global__ void k_conv_x(const float4* __restrict__ x, bfx4* __restrict__ xb, int n4) {
  int i = blockIdx.x * blockDim.x + threadIdx.x;
  int stride = gridDim.x * blockDim.x;
  for (; i < n4; i += stride) {
    float4 v = x[i];
    bfx4 o;
    o[0] = (__bf16)v.x; o[1] = (__bf16)v.y; o[2] = (__bf16)v.z; o[3] = (__bf16)v.w;
    xb[i] = o;
  }
}

__global__ void k_conv_w(const float4* __restrict__ w, const float* __restrict__ lam,
                         bfx4* __restrict__ w1b, bfx4* __restrict__ w2b) {
  const int n4 = 4096 * 1024 / 4;
  const float l0 = lam[0], l1 = lam[1];
  int i = blockIdx.x * blockDim.x + threadIdx.x;
  int stride = gridDim.x * blockDim.x;
  for (; i < n4; i += stride) {
    int row = (i * 4) >> 10;
    float s = (row < 3 * DIMM) ? l0 : l1;
    float4 v = w[i];
    bfx4 o;
    o[0] = (__bf16)(s * v.x); o[1] = (__bf16)(s * v.y);
    o[2] = (__bf16)(s * v.z); o[3] = (__bf16)(s * v.w);
    if (row < 3 * DIMM) w1b[i] = o;
    else                w2b[i - 3 * DIMM * DIMM / 4] = o;
  }
}

// ---------------- pipelined GEMM: C[M,N] = A[M,K] * B[N,K]^T ----------------
// BMxBN tile, BK=64, 8 waves (2x4), double-buffered LDS with st_16x32 swizzle,
// staging issued one full K-tile ahead, single vmcnt(0)+barrier per tile.
template <int BM, int BN, typename CT>
__global__ __launch_bounds__(512, 2) void k_gemm8(const __bf16* __restrict__ A,
                                                  const __bf16* __restrict__ B,
                                                  CT* __restrict__ C,
                                                  int M, int N, int K) {
  constexpr int MF = BM / 32;  // A fragments per wave (wave covers BM/2 rows)
  constexpr int NF = BN / 64;  // B fragments per wave (wave covers BN/4 cols)
  constexpr int CA = BM / 64;  // A staging chunks (64 rows x 64 cols = 8KB each)
  constexpr int CB = BN / 64;
  __shared__ __bf16 As0[BM * 64], Bs0[BN * 64], As1[BM * 64], Bs1[BN * 64];

  const int tid = threadIdx.x;
  const int wave = tid >> 6, lane = tid & 63;
  const int wm = wave >> 2, wn = wave & 3;
  const int lr = lane & 15, lg = lane >> 4;
  const int swz = (lr & 4) << 3;  // st_16x32: byte ^= ((byte>>9)&1)<<5, row&4 == lr&4

  const int bm = blockIdx.x, bn = blockIdx.y;

  // staging source (global col pre-swizzled so linear LDS + swizzled read match)
  const int srow = tid >> 3;
  const int scol = ((tid & 7) * 8) ^ (((tid >> 5) & 1) << 4);
  const __bf16* Ag = A + (size_t)(bm * BM + srow) * K + scol;
  const __bf16* Bg = B + (size_t)(bn * BN + srow) * K + scol;

  f32x4 acc[MF][NF] = {};

  auto stage = [&](int kt, __bf16* Asb, __bf16* Bsb) {
#pragma unroll
    for (int c = 0; c < CA; c++)
      GLDS16(Ag + (size_t)c * 64 * K + kt * 64, (char*)Asb + c * 8192 + wave * 1024);
#pragma unroll
    for (int c = 0; c < CB; c++)
      GLDS16(Bg + (size_t)c * 64 * K + kt * 64, (char*)Bsb + c * 8192 + wave * 1024);
    __builtin_amdgcn_sched_barrier(0);  // keep staging issues ahead of ds_reads
  };

  auto compute = [&](const __bf16* Asb, const __bf16* Bsb) {
    const char* Ab = (const char*)Asb + (((wm * (BM / 2) + lr) * 128 + lg * 16) ^ swz);
    const char* Bb = (const char*)Bsb + (((wn * (BN / 4) + lr) * 128 + lg * 16) ^ swz);
    bfx8 bfr[NF][2];
#pragma unroll
    for (int nf = 0; nf < NF; nf++)
#pragma unroll
      for (int kk = 0; kk < 2; kk++)
        bfr[nf][kk] = *(const bfx8*)(Bb + nf * 2048 + kk * 64);
#pragma unroll
    for (int mh = 0; mh < 2; mh++) {
      bfx8 af[MF / 2][2];
#pragma unroll
      for (int i = 0; i < MF / 2; i++)
#pragma unroll
        for (int kk = 0; kk < 2; kk++)
          af[i][kk] = *(const bfx8*)(Ab + (mh * (MF / 2) + i) * 2048 + kk * 64);
      __builtin_amdgcn_s_setprio(1);
#pragma unroll
      for (int i = 0; i < MF / 2; i++)
#pragma unroll
        for (int nf = 0; nf < NF; nf++)
#pragma unroll
          for (int kk = 0; kk < 2; kk++)
            acc[mh * (MF / 2) + i][nf] = __builtin_amdgcn_mfma_f32_16x16x32_bf16(
                af[i][kk], bfr[nf][kk], acc[mh * (MF / 2) + i][nf], 0, 0, 0);
      __builtin_amdgcn_s_setprio(0);
    }
  };

  const int nt = K / 64;  // K=1024 -> 16 tiles (even)
  stage(0, As0, Bs0);
  if (nt > 1) stage(1, As1, Bs1);
  asm volatile("s_waitcnt vmcnt(%0)" ::"i"(CA + CB) : "memory");  // tile0 landed
  __builtin_amdgcn_s_barrier();

  for (int t2 = 0; t2 < nt; t2 += 2) {
    compute(As0, Bs0);
    asm volatile("s_waitcnt vmcnt(0)" ::: "memory");  // tile t2+1 landed
    __builtin_amdgcn_s_barrier();
    if (t2 + 2 < nt) stage(t2 + 2, As0, Bs0);
    compute(As1, Bs1);
    asm volatile("s_waitcnt vmcnt(0)" ::: "memory");  // tile t2+2 landed
    __builtin_amdgcn_s_barrier();
    if (t2 + 3 < nt) stage(t2 + 3, As1, Bs1);
  }

  const int rbase = bm * BM + wm * (BM / 2) + lg * 4;
  const int cbase = bn * BN + wn * (BN / 4) + lr;
#pragma unroll
  for (int mf = 0; mf < MF; mf++)
#pragma unroll
    for (int rr = 0; rr < 4; rr++) {
      size_t rowoff = (size_t)(rbase + mf * 16 + rr) * N + cbase;
#pragma unroll
      for (int nf = 0; nf < NF; nf++) C[rowoff + nf * 16] = (CT)acc[mf][nf][rr];
    }
}

// ---------------- q/k postprocess: RMS, RoPE, key-offset ----------------
__global__ __launch_bounds__(512) void k_qk(
    const __bf16* __restrict__ qkv, const float* __restrict__ f1,
    const float* __restrict__ f2, const int* __restrict__ koff_p,
    __bf16* __restrict__ qb, __bf16* __restrict__ kb) {
  const int t = blockIdx.x;
  const int h = threadIdx.x >> 6;
  const int l = threadIdx.x & 63;
  const int d0 = 2 * l;
  const size_t qoff = (size_t)t * (3 * DIMM) + h * HD;

  bfx2 qv = *(const bfx2*)&qkv[qoff + d0];
  bfx2 kv = *(const bfx2*)&qkv[qoff + DIMM + d0];
  float q0 = (float)qv[0], q1 = (float)qv[1];
  float k0 = (float)kv[0], k1 = (float)kv[1];

  float sq = q0 * q0 + q1 * q1;
  float sk = k0 * k0 + k1 * k1;
#pragma unroll
  for (int off = 32; off; off >>= 1) {
    sq += __shfl_xor(sq, off);
    sk += __shfl_xor(sk, off);
  }
  float rq = rsqrtf(sq * (1.0f / 128.0f) + RMS_EPS);
  float rk = rsqrtf(sk * (1.0f / 128.0f) + RMS_EPS);
  q0 *= rq; q1 *= rq; k0 *= rk; k1 *= rk;

  float2 cc = *(const float2*)&f1[(size_t)t * HD + d0];
  float2 ss = *(const float2*)&f2[(size_t)t * HD + d0];
  float rq0 = cc.x * q0 + ss.x * q1, rq1 = cc.y * q1 + ss.y * q0;
  float rk0 = cc.x * k0 + ss.x * k1, rk1 = cc.y * k1 + ss.y * k0;

  bfx2 qo; qo[0] = (__bf16)rq0; qo[1] = (__bf16)rq1;
  *(bfx2*)&qb[(size_t)t * DIMM + h * HD + d0] = qo;

  bfx2 ko2; ko2[0] = (__bf16)rk0; ko2[1] = (__bf16)rk1;
  const int koff = *koff_p;
  const size_t kcol = (size_t)h * HD + d0;
  if (!koff || l < 32) {
    *(bfx2*)&kb[(size_t)t * DIMM + kcol] = ko2;
  } else {
    if (t + 1 < TSEQ) *(bfx2*)&kb[(size_t)(t + 1) * DIMM + kcol] = ko2;
    if (t == 0)       *(bfx2*)&kb[kcol] = ko2;
  }
}

// ---------------- v postprocess: gates + ve-gate + LDS-tiled transpose ----------------
__global__ __launch_bounds__(512) void k_vgate(
    const __bf16* __restrict__ qkv, const float* __restrict__ x,
    const float* __restrict__ ve, const float* __restrict__ agw,
    const float* __restrict__ vgw, __bf16* __restrict__ vT,
    float* __restrict__ ag) {
  __shared__ float vg_lds[64][4];
  __shared__ __bf16 vtile[HD][68];
  const int t0 = blockIdx.x * 64;
  const int hbase = blockIdx.y * 4;
  const int tid = threadIdx.x;

  if (tid < 256) {
    const int tl = tid >> 2, hh = tid & 3;
    const int h = hbase + hh;
    const int t = t0 + tl;
    float za = 0.0f, zg = 0.0f;
#pragma unroll
    for (int j = 0; j < 12; j++) {
      float xv = x[(size_t)t * DIMM + j];
      za += xv * agw[h * 12 + j];
      zg += xv * vgw[h * 12 + j];
    }
    ag[(size_t)t * NHEAD + h] = sig_(za);
    vg_lds[tl][hh] = 2.0f * sig_(zg);
  }
  __syncthreads();

  const int w = tid >> 6, l = tid & 63;
  const int dout = tid >> 2, tof = (tid & 3) * 16;
  for (int hh = 0; hh < 4; hh++) {
    const int h = hbase + hh;
#pragma unroll
    for (int it = 0; it < 8; it++) {
      const int tl = w * 8 + it;
      const int t = t0 + tl;
      const size_t voff = (size_t)t * (3 * DIMM) + 2 * DIMM + h * HD;
      float va = (float)qkv[voff + l];
      float vb = (float)qkv[voff + l + 64];
      float vea = ve[(size_t)t * DIMM + h * HD + l];
      float veb = ve[(size_t)t * DIMM + h * HD + l + 64];
      float gv = vg_lds[tl][hh];
      vtile[l][tl]      = (__bf16)(va + gv * vea);
      vtile[l + 64][tl] = (__bf16)(vb + gv * veb);
    }
    __syncthreads();
    {
      bfx4 a0 = *(const bfx4*)&vtile[dout][tof];
      bfx4 a1 = *(const bfx4*)&vtile[dout][tof + 4];
      bfx4 a2 = *(const bfx4*)&vtile[dout][tof + 8];
      bfx4 a3 = *(const bfx4*)&vtile[dout][tof + 12];
      bfx8 p0, p1;
      p0[0]=a0[0]; p0[1]=a0[1]; p0[2]=a0[2]; p0[3]=a0[3];
      p0[4]=a1[0]; p0[5]=a1[1]; p0[6]=a1[2]; p0[7]=a1[3];
      p1[0]=a2[0]; p1[1]=a2[1]; p1[2]=a2[2]; p1[3]=a2[3];
      p1[4]=a3[0]; p1[5]=a3[1]; p1[6]=a3[2]; p1[7]=a3[3];
      __bf16* dst = &vT[(size_t)(h * HD + dout) * TSEQ + t0 + tof];
      *(bfx8*)dst = p0;
      *(bfx8*)(dst + 8) = p1;
    }
    __syncthreads();
  }
}

// ---------------- windowed varlen flash attention ----------------
__global__ __launch_bounds__(256) void k_attn(
    const __bf16* __restrict__ qb, const __bf16* __restrict__ kb,
    const __bf16* __restrict__ vT, const float* __restrict__ ag,
    const int* __restrict__ sl, int ns, __bf16* __restrict__ yb) {
  __shared__ __bf16 p_lds[4][32][64];
  const int n = blockIdx.x, h = blockIdx.y;
  const int w = threadIdx.x >> 6, l = threadIdx.x & 63;
  const int lr = l & 15, lg = l >> 4;
  const int ko = lg * 8;
  const int q0r = n * 128 + w * 32;

  bfx8 qf[2][4];
#pragma unroll
  for (int m = 0; m < 2; m++)
#pragma unroll
    for (int s = 0; s < 4; s++)
      qf[m][s] = *(const bfx8*)&qb[(size_t)(q0r + m * 16 + lr) * DIMM + h * HD + s * 32 + ko];

  int segq[2][4];
#pragma unroll
  for (int m = 0; m < 2; m++)
#pragma unroll
    for (int rr = 0; rr < 4; rr++)
      segq[m][rr] = segof_(q0r + m * 16 + lg * 4 + rr, sl, ns);

  f32x4 o[2][8] = {};
  float mr[2][4], lsum[2][4];
#pragma unroll
  for (int m = 0; m < 2; m++)
#pragma unroll
    for (int rr = 0; rr < 4; rr++) { mr[m][rr] = -1e30f; lsum[m][rr] = 0.0f; }

  for (int kbk = 0; kbk < 4; kbk++) {
    if (n == 0 && kbk < 2) continue;
    const int kbase = kbk * 64;

    f32x4 sf[2][4] = {};
#pragma unroll
    for (int s = 0; s < 4; s++) {
#pragma unroll
      for (int kf = 0; kf < 4; kf++) {
        int key = n * 128 - 128 + kbase + kf * 16 + lr;
        bfx8 bfr = *(const bfx8*)&kb[(size_t)key * DIMM + h * HD + s * 32 + ko];
#pragma unroll
        for (int m = 0; m < 2; m++)
          sf[m][kf] = __builtin_amdgcn_mfma_f32_16x16x32_bf16(qf[m][s], bfr, sf[m][kf], 0, 0, 0);
      }
    }

    int gk[4], segk[4];
#pragma unroll
    for (int kf = 0; kf < 4; kf++) {
      gk[kf] = n * 128 - 128 + kbase + kf * 16 + lr;
      segk[kf] = (gk[kf] >= 0) ? segof_(gk[kf], sl, ns) : -1;
    }
#pragma unroll
    for (int m = 0; m < 2; m++)
#pragma unroll
      for (int rr = 0; rr < 4; rr++) {
        int row = w * 32 + m * 16 + lg * 4 + rr;
#pragma unroll
        for (int kf = 0; kf < 4; kf++) {
          int ki = kbase + kf * 16 + lr;
          bool valid = (gk[kf] >= 0) && (ki >= row) && (ki <= row + 128) &&
                       (segk[kf] == segq[m][rr]);
          float sv = sf[m][kf][rr];
          sf[m][kf][rr] = valid ? sv * ATTN_SCALE : -1e30f;
        }
      }

#pragma unroll
    for (int m = 0; m < 2; m++)
#pragma unroll
      for (int rr = 0; rr < 4; rr++) {
        float mx = fmaxf(fmaxf(sf[m][0][rr], sf[m][1][rr]), fmaxf(sf[m][2][rr], sf[m][3][rr]));
#pragma unroll
        for (int off = 8; off; off >>= 1) mx = fmaxf(mx, __shfl_xor(mx, off));
        float mnew = fmaxf(mr[m][rr], mx);
        float corr = __expf(mr[m][rr] - mnew);
        float ls = 0.0f;
#pragma unroll
        for (int kf = 0; kf < 4; kf++) {
          float sv = sf[m][kf][rr];
          float p = (sv <= -1e29f) ? 0.0f : __expf(sv - mnew);
          sf[m][kf][rr] = p;
          ls += p;
        }
#pragma unroll
        for (int off = 8; off; off >>= 1) ls += __shfl_xor(ls, off);
        lsum[m][rr] = lsum[m][rr] * corr + ls;
        mr[m][rr] = mnew;
#pragma unroll
        for (int nf = 0; nf < 8; nf++) o[m][nf][rr] *= corr;
      }

#pragma unroll
    for (int m = 0; m < 2; m++)
#pragma unroll
      for (int kf = 0; kf < 4; kf++)
#pragma unroll
        for (int rr = 0; rr < 4; rr++)
          p_lds[w][m * 16 + lg * 4 + rr][kf * 16 + lr] = (__bf16)sf[m][kf][rr];

#pragma unroll
    for (int s2 = 0; s2 < 2; s2++) {
      bfx8 af[2];
#pragma unroll
      for (int m = 0; m < 2; m++) af[m] = *(const bfx8*)&p_lds[w][m * 16 + lr][s2 * 32 + ko];
      int keyg = n * 128 - 128 + kbase + s2 * 32 + ko;
#pragma unroll
      for (int nf = 0; nf < 8; nf++) {
        bfx8 bfr = *(const bfx8*)&vT[(size_t)(h * HD + nf * 16 + lr) * TSEQ + keyg];
#pragma unroll
        for (int m = 0; m < 2; m++)
          o[m][nf] = __builtin_amdgcn_mfma_f32_16x16x32_bf16(af[m], bfr, o[m][nf], 0, 0, 0);
      }
    }
  }

#pragma unroll
  for (int m = 0; m < 2; m++)
#pragma unroll
    for (int rr = 0; rr < 4; rr++) {
      int gq = q0r + m * 16 + lg * 4 + rr;
      float sc = (1.0f / lsum[m][rr]) * ag[(size_t)gq * NHEAD + h];
#pragma unroll
      for (int nf = 0; nf < 8; nf++)
        yb[(size_t)gq * DIMM + h * HD + nf * 16 + lr] = (__bf16)(o[m][nf][rr] * sc);
    }
}

// ---------------- launch ----------------
extern "C" void kernel_launch(void* const* d_in, const int* in_sizes, int n_in,
                              void* d_out, int out_size, void* d_ws, size_t ws_size,
                              hipStream_t stream) {
  const float* x   = (const float*)d_in[0];
  const float* qw  = (const float*)d_in[1];
  const float* ve  = (const float*)d_in[2];
  const float* lam = (const float*)d_in[3];
  const float* f1  = (const float*)d_in[4];
  const float* f2  = (const float*)d_in[5];
  const float* agw = (const float*)d_in[6];
  const float* vgw = (const float*)d_in[7];
  const int*   sl  = (const int*)d_in[8];
  const int    ns  = in_sizes[8];
  const int*   koff = (const int*)d_in[10];
  float* out = (float*)d_out;
  char* ws = (char*)d_ws;

  const size_t MB = 1024 * 1024;
  if (ws_size < 105 * MB) return;
  __bf16* xb   = (__bf16*)(ws);
  __bf16* w1b  = (__bf16*)(ws + 16 * MB);
  __bf16* w2b  = (__bf16*)(ws + 22 * MB);
  __bf16* qkvb = (__bf16*)(ws + 24 * MB);
  __bf16* qbuf = (__bf16*)(ws + 72 * MB);
  __bf16* kbuf = (__bf16*)(ws + 88 * MB);
  float*  ag   = (float*)(ws + 104 * MB);
  __bf16* vT   = xb;    // xb dead after GEMM1
  __bf16* ybuf = qkvb;  // qkvb dead after k_qk/k_vgate

  k_conv_x<<<2048, 256, 0, stream>>>((const float4*)x, (bfx4*)xb, TSEQ * DIMM / 4);
  k_conv_w<<<1024, 256, 0, stream>>>((const float4*)qw, lam, (bfx4*)w1b, (bfx4*)w2b);
  k_gemm8<256, 256, __bf16><<<dim3(TSEQ / 256, 3 * DIMM / 256), 512, 0, stream>>>(
      xb, w1b, qkvb, TSEQ, 3 * DIMM, DIMM);
  k_qk<<<TSEQ, 512, 0, stream>>>(qkvb, f1, f2, koff, qbuf, kbuf);
  k_vgate<<<dim3(TSEQ / 64, 2), 512, 0, stream>>>(qkvb, x, ve, agw, vgw, vT, ag);
  k_attn<<<dim3(TSEQ / 128, NHEAD), 256, 0, stream>>>(qbuf, kbuf, vT, ag, sl, ns, ybuf);
  k_gemm8<128, 256, float><<<dim3(TSEQ / 128, DIMM / 256), 512, 0, stream>>>(
      ybuf, w2b, out, TSEQ, DIMM, DIMM);
}

// Round 4
// 196.132 us; speedup vs baseline: 1.2428x; 1.0462x over previous
//
#include <hip/hip_runtime.h>

// Fused attention block for MI355X (gfx950).
// Pipeline: conv(x,W) -> GEMM1(qkv) -> k_qk(RMS/RoPE/shift) + k_vgate(gates,vT) ->
//           windowed flash attention -> GEMM2 -> d_out (f32)

#define TSEQ 8192
#define DIMM 1024
#define NHEAD 8
#define HD 128
#define ATTN_SCALE 0.1f
#define RMS_EPS 1.1920929e-07f

typedef __bf16 bfx2 __attribute__((ext_vector_type(2)));
typedef __bf16 bfx4 __attribute__((ext_vector_type(4)));
typedef __bf16 bfx8 __attribute__((ext_vector_type(8)));
typedef float f32x4 __attribute__((ext_vector_type(4)));

#define GLDS16(g, l)                                                         \
  __builtin_amdgcn_global_load_lds(                                          \
      (const __attribute__((address_space(1))) void*)(g),                    \
      (__attribute__((address_space(3))) void*)(l), 16, 0, 0)

__device__ __forceinline__ float sig_(float z) { return 1.0f / (1.0f + __expf(-z)); }

__device__ __forceinline__ int segof_(int t, const int* __restrict__ sl, int ns) {
  int c = 0;
  for (int i = 0; i < ns; i++) c += (sl[i] <= t);
  return c;
}

// ---------------- f32 -> bf16 conversions ----------------
__global__ void k_conv_x(const float4* __restrict__ x, bfx4* __restrict__ xb, int n4) {
  int i = blockIdx.x * blockDim.x + threadIdx.x;
  int stride = gridDim.x * blockDim.x;
  for (; i < n4; i += stride) {
    float4 v = x[i];
    bfx4 o;
    o[0] = (__bf16)v.x; o[1] = (__bf16)v.y; o[2] = (__bf16)v.z; o[3] = (__bf16)v.w;
    xb[i] = o;
  }
}

__global__ void k_conv_w(const float4* __restrict__ w, const float* __restrict__ lam,
                         bfx4* __restrict__ w1b, bfx4* __restrict__ w2b) {
  const int n4 = 4096 * 1024 / 4;
  const float l0 = lam[0], l1 = lam[1];
  int i = blockIdx.x * blockDim.x + threadIdx.x;
  int stride = gridDim.x * blockDim.x;
  for (; i < n4; i += stride) {
    int row = (i * 4) >> 10;
    float s = (row < 3 * DIMM) ? l0 : l1;
    float4 v = w[i];
    bfx4 o;
    o[0] = (__bf16)(s * v.x); o[1] = (__bf16)(s * v.y);
    o[2] = (__bf16)(s * v.z); o[3] = (__bf16)(s * v.w);
    if (row < 3 * DIMM) w1b[i] = o;
    else                w2b[i - 3 * DIMM * DIMM / 4] = o;
  }
}

// ---------------- 8-phase pipelined GEMM: C[M,N] = A[M,K] * B[N,K]^T ----------------
// m201-style schedule: BK=64, 2 K-tiles/iter, 8 phases/iter, double-buffered LDS,
// counted vmcnt (never 0 in steady state), (row&7) XOR slot swizzle, setprio MFMA.
// 8 waves as 2(M) x 4(N); wave output = (BM/2) x (BN/4).
template <int BM, int BN, typename CT>
__global__ __launch_bounds__(512, 2) void k_gemm8p(const __bf16* __restrict__ A,
                                                   const __bf16* __restrict__ B,
                                                   CT* __restrict__ C,
                                                   int M, int N, int K) {
  constexpr int MF = BM / 32, NF = BN / 64;   // frags per wave
  constexpr int MH = MF / 2, NH = NF / 2;     // frags per half
  constexpr int LA = BM / 128, LB = BN / 128; // global_load_lds per half-tile stage
  __shared__ __bf16 lds[2][(BM + BN) * 64];

  const int tid = threadIdx.x;
  const int wave = tid >> 6, lane = tid & 63;
  const int wm = wave >> 2, wn = wave & 3;
  const int lr = lane & 15, lg = lane >> 4;

  const int bm = blockIdx.x, bn = blockIdx.y;

  // staging: thread covers LDS row (tid>>3), 16B slot (tid&7); global source col
  // pre-swizzled by (row&7) so linear LDS write + swizzled ds_read match.
  const int srow = tid >> 3;
  const int scol = ((tid & 7) ^ (srow & 7)) * 8;
  const __bf16* Ag = A + (size_t)(bm * BM + srow) * K + scol;
  const __bf16* Bg = B + (size_t)(bn * BN + srow) * K + scol;

  char* lds0 = (char*)&lds[0][0];
  char* lds1 = (char*)&lds[1][0];

  auto stageA = [&](int kt, int hf, char* buf) {
#pragma unroll
    for (int L = 0; L < LA; L++)
      GLDS16(Ag + (size_t)(hf * (BM / 2) + L * 64) * K + kt * 64,
             buf + hf * (BM / 2) * 128 + L * 8192 + wave * 1024);
  };
  auto stageB = [&](int kt, int hf, char* buf) {
#pragma unroll
    for (int L = 0; L < LB; L++)
      GLDS16(Bg + (size_t)(hf * (BN / 2) + L * 64) * K + kt * 64,
             buf + BM * 128 + hf * (BN / 2) * 128 + L * 8192 + wave * 1024);
  };

  const int aoffs = (wm * (BM / 2) + lr) * 128;
  const int boffs = BM * 128 + (wn * (BN / 4) + lr) * 128;
  const int s0 = (lg ^ (lr & 7)) * 16;        // kk=0 swizzled slot
  const int s1 = ((4 + lg) ^ (lr & 7)) * 16;  // kk=1

  f32x4 acc[MF][NF] = {};
  bfx8 af[MH][2], bfr[NF][2];

  auto readA = [&](char* buf, int hf) {
#pragma unroll
    for (int i = 0; i < MH; i++) {
      const char* p = buf + aoffs + (hf * MH + i) * 2048;
      af[i][0] = *(const bfx8*)(p + s0);
      af[i][1] = *(const bfx8*)(p + s1);
    }
  };
  auto readB = [&](char* buf, int hb) {
#pragma unroll
    for (int i = 0; i < NH; i++) {
      const char* p = buf + boffs + (hb * NH + i) * 2048;
      bfr[hb * NH + i][0] = *(const bfx8*)(p + s0);
      bfr[hb * NH + i][1] = *(const bfx8*)(p + s1);
    }
  };
  auto mmaQ = [&](int ha, int hb) {
    __builtin_amdgcn_s_setprio(1);
#pragma unroll
    for (int i = 0; i < MH; i++)
#pragma unroll
      for (int jq = 0; jq < NH; jq++)
#pragma unroll
        for (int kk = 0; kk < 2; kk++)
          acc[ha * MH + i][hb * NH + jq] = __builtin_amdgcn_mfma_f32_16x16x32_bf16(
              af[i][kk], bfr[hb * NH + jq][kk], acc[ha * MH + i][hb * NH + jq], 0, 0, 0);
    __builtin_amdgcn_s_setprio(0);
  };

#define BAR() __builtin_amdgcn_s_barrier()
#define LGKM0() asm volatile("s_waitcnt lgkmcnt(0)" ::: "memory")

  // prologue: tile0 fully + Alo(tile1); wait tile0 (leave Alo1 in flight)
  stageA(0, 0, lds0); stageA(0, 1, lds0); stageB(0, 0, lds0); stageB(0, 1, lds0);
  stageA(1, 0, lds1);
  asm volatile("s_waitcnt vmcnt(%0)" ::"i"(LA) : "memory");
  BAR();

  const int NT2 = K / 128;  // iters; 2 K-tiles each
  for (int j = 0; j < NT2; j++) {
    const bool more = (j + 1 < NT2);
    const int t1 = 2 * j + 1;
    // ph0: Q(A0,B0) buf0; stage Ahi(t1)->buf1
    readA(lds0, 0); readB(lds0, 0);
    stageA(t1, 1, lds1);
    BAR(); LGKM0(); mmaQ(0, 0); BAR();
    // ph1: Q(A0,B1); stage Blo(t1)->buf1
    readB(lds0, 1);
    stageB(t1, 0, lds1);
    BAR(); LGKM0(); mmaQ(0, 1); BAR();
    // ph2: Q(A1,B0); stage Bhi(t1)->buf1
    readA(lds0, 1);
    stageB(t1, 1, lds1);
    BAR(); LGKM0(); mmaQ(1, 0); BAR();
    // ph3: Q(A1,B1); stage Alo(t1+1)->buf0; wait t1 landed (allow Alo(t1+1) in flight)
    if (more) stageA(t1 + 1, 0, lds0);
    BAR(); LGKM0(); mmaQ(1, 1);
    if (more) { asm volatile("s_waitcnt vmcnt(%0)" ::"i"(LA) : "memory"); }
    else      { asm volatile("s_waitcnt vmcnt(0)" ::: "memory"); }
    BAR();
    // ph4: Q(A0,B0) buf1; stage Ahi(t1+1)->buf0
    readA(lds1, 0); readB(lds1, 0);
    if (more) stageA(t1 + 1, 1, lds0);
    BAR(); LGKM0(); mmaQ(0, 0); BAR();
    // ph5: Q(A0,B1); stage Blo(t1+1)->buf0
    readB(lds1, 1);
    if (more) stageB(t1 + 1, 0, lds0);
    BAR(); LGKM0(); mmaQ(0, 1); BAR();
    // ph6: Q(A1,B0); stage Bhi(t1+1)->buf0
    readA(lds1, 1);
    if (more) stageB(t1 + 1, 1, lds0);
    BAR(); LGKM0(); mmaQ(1, 0); BAR();
    // ph7: Q(A1,B1); stage Alo(t1+2)->buf1; wait t1+1 landed
    if (more) stageA(t1 + 2, 0, lds1);
    BAR(); LGKM0(); mmaQ(1, 1);
    if (more) { asm volatile("s_waitcnt vmcnt(%0)" ::"i"(LA) : "memory"); }
    else      { asm volatile("s_waitcnt vmcnt(0)" ::: "memory"); }
    BAR();
  }

  // epilogue: C/D layout col = lane&15, row = (lane>>4)*4 + reg
  const int rbase = bm * BM + wm * (BM / 2) + lg * 4;
  const int cbase = bn * BN + wn * (BN / 4) + lr;
#pragma unroll
  for (int f = 0; f < MF; f++)
#pragma unroll
    for (int rr = 0; rr < 4; rr++) {
      size_t rowoff = (size_t)(rbase + f * 16 + rr) * N + cbase;
#pragma unroll
      for (int nf = 0; nf < NF; nf++) C[rowoff + nf * 16] = (CT)acc[f][nf][rr];
    }
#undef BAR
#undef LGKM0
}

// ---------------- q/k postprocess: RMS, RoPE, key-offset ----------------
__global__ __launch_bounds__(512) void k_qk(
    const __bf16* __restrict__ qkv, const float* __restrict__ f1,
    const float* __restrict__ f2, const int* __restrict__ koff_p,
    __bf16* __restrict__ qb, __bf16* __restrict__ kb) {
  const int t = blockIdx.x;
  const int h = threadIdx.x >> 6;
  const int l = threadIdx.x & 63;
  const int d0 = 2 * l;
  const size_t qoff = (size_t)t * (3 * DIMM) + h * HD;

  bfx2 qv = *(const bfx2*)&qkv[qoff + d0];
  bfx2 kv = *(const bfx2*)&qkv[qoff + DIMM + d0];
  float q0 = (float)qv[0], q1 = (float)qv[1];
  float k0 = (float)kv[0], k1 = (float)kv[1];

  float sq = q0 * q0 + q1 * q1;
  float sk = k0 * k0 + k1 * k1;
#pragma unroll
  for (int off = 32; off; off >>= 1) {
    sq += __shfl_xor(sq, off);
    sk += __shfl_xor(sk, off);
  }
  float rq = rsqrtf(sq * (1.0f / 128.0f) + RMS_EPS);
  float rk = rsqrtf(sk * (1.0f / 128.0f) + RMS_EPS);
  q0 *= rq; q1 *= rq; k0 *= rk; k1 *= rk;

  float2 cc = *(const float2*)&f1[(size_t)t * HD + d0];
  float2 ss = *(const float2*)&f2[(size_t)t * HD + d0];
  float rq0 = cc.x * q0 + ss.x * q1, rq1 = cc.y * q1 + ss.y * q0;
  float rk0 = cc.x * k0 + ss.x * k1, rk1 = cc.y * k1 + ss.y * k0;

  bfx2 qo; qo[0] = (__bf16)rq0; qo[1] = (__bf16)rq1;
  *(bfx2*)&qb[(size_t)t * DIMM + h * HD + d0] = qo;

  bfx2 ko2; ko2[0] = (__bf16)rk0; ko2[1] = (__bf16)rk1;
  const int koff = *koff_p;
  const size_t kcol = (size_t)h * HD + d0;
  if (!koff || l < 32) {
    *(bfx2*)&kb[(size_t)t * DIMM + kcol] = ko2;
  } else {
    if (t + 1 < TSEQ) *(bfx2*)&kb[(size_t)(t + 1) * DIMM + kcol] = ko2;
    if (t == 0)       *(bfx2*)&kb[kcol] = ko2;
  }
}

// ---------------- v postprocess: gates + ve-gate + LDS-tiled transpose ----------------
__global__ __launch_bounds__(512) void k_vgate(
    const __bf16* __restrict__ qkv, const float* __restrict__ x,
    const float* __restrict__ ve, const float* __restrict__ agw,
    const float* __restrict__ vgw, __bf16* __restrict__ vT,
    float* __restrict__ ag) {
  __shared__ float vg_lds[64][4];
  __shared__ __bf16 vtile[HD][68];
  const int t0 = blockIdx.x * 64;
  const int hbase = blockIdx.y * 4;
  const int tid = threadIdx.x;

  if (tid < 256) {
    const int tl = tid >> 2, hh = tid & 3;
    const int h = hbase + hh;
    const int t = t0 + tl;
    float za = 0.0f, zg = 0.0f;
#pragma unroll
    for (int j = 0; j < 12; j++) {
      float xv = x[(size_t)t * DIMM + j];
      za += xv * agw[h * 12 + j];
      zg += xv * vgw[h * 12 + j];
    }
    ag[(size_t)t * NHEAD + h] = sig_(za);
    vg_lds[tl][hh] = 2.0f * sig_(zg);
  }
  __syncthreads();

  const int w = tid >> 6, l = tid & 63;
  const int dout = tid >> 2, tof = (tid & 3) * 16;
  for (int hh = 0; hh < 4; hh++) {
    const int h = hbase + hh;
#pragma unroll
    for (int it = 0; it < 8; it++) {
      const int tl = w * 8 + it;
      const int t = t0 + tl;
      const size_t voff = (size_t)t * (3 * DIMM) + 2 * DIMM + h * HD;
      float va = (float)qkv[voff + l];
      float vb = (float)qkv[voff + l + 64];
      float vea = ve[(size_t)t * DIMM + h * HD + l];
      float veb = ve[(size_t)t * DIMM + h * HD + l + 64];
      float gv = vg_lds[tl][hh];
      vtile[l][tl]      = (__bf16)(va + gv * vea);
      vtile[l + 64][tl] = (__bf16)(vb + gv * veb);
    }
    __syncthreads();
    {
      bfx4 a0 = *(const bfx4*)&vtile[dout][tof];
      bfx4 a1 = *(const bfx4*)&vtile[dout][tof + 4];
      bfx4 a2 = *(const bfx4*)&vtile[dout][tof + 8];
      bfx4 a3 = *(const bfx4*)&vtile[dout][tof + 12];
      bfx8 p0, p1;
      p0[0]=a0[0]; p0[1]=a0[1]; p0[2]=a0[2]; p0[3]=a0[3];
      p0[4]=a1[0]; p0[5]=a1[1]; p0[6]=a1[2]; p0[7]=a1[3];
      p1[0]=a2[0]; p1[1]=a2[1]; p1[2]=a2[2]; p1[3]=a2[3];
      p1[4]=a3[0]; p1[5]=a3[1]; p1[6]=a3[2]; p1[7]=a3[3];
      __bf16* dst = &vT[(size_t)(h * HD + dout) * TSEQ + t0 + tof];
      *(bfx8*)dst = p0;
      *(bfx8*)(dst + 8) = p1;
    }
    __syncthreads();
  }
}

// ---------------- windowed varlen flash attention ----------------
__global__ __launch_bounds__(256) void k_attn(
    const __bf16* __restrict__ qb, const __bf16* __restrict__ kb,
    const __bf16* __restrict__ vT, const float* __restrict__ ag,
    const int* __restrict__ sl, int ns, __bf16* __restrict__ yb) {
  __shared__ __bf16 p_lds[4][32][64];
  const int n = blockIdx.x, h = blockIdx.y;
  const int w = threadIdx.x >> 6, l = threadIdx.x & 63;
  const int lr = l & 15, lg = l >> 4;
  const int ko = lg * 8;
  const int q0r = n * 128 + w * 32;

  bfx8 qf[2][4];
#pragma unroll
  for (int m = 0; m < 2; m++)
#pragma unroll
    for (int s = 0; s < 4; s++)
      qf[m][s] = *(const bfx8*)&qb[(size_t)(q0r + m * 16 + lr) * DIMM + h * HD + s * 32 + ko];

  int segq[2][4];
#pragma unroll
  for (int m = 0; m < 2; m++)
#pragma unroll
    for (int rr = 0; rr < 4; rr++)
      segq[m][rr] = segof_(q0r + m * 16 + lg * 4 + rr, sl, ns);

  f32x4 o[2][8] = {};
  float mr[2][4], lsum[2][4];
#pragma unroll
  for (int m = 0; m < 2; m++)
#pragma unroll
    for (int rr = 0; rr < 4; rr++) { mr[m][rr] = -1e30f; lsum[m][rr] = 0.0f; }

  for (int kbk = 0; kbk < 4; kbk++) {
    if (n == 0 && kbk < 2) continue;
    const int kbase = kbk * 64;

    f32x4 sf[2][4] = {};
#pragma unroll
    for (int s = 0; s < 4; s++) {
#pragma unroll
      for (int kf = 0; kf < 4; kf++) {
        int key = n * 128 - 128 + kbase + kf * 16 + lr;
        bfx8 bfr = *(const bfx8*)&kb[(size_t)key * DIMM + h * HD + s * 32 + ko];
#pragma unroll
        for (int m = 0; m < 2; m++)
          sf[m][kf] = __builtin_amdgcn_mfma_f32_16x16x32_bf16(qf[m][s], bfr, sf[m][kf], 0, 0, 0);
      }
    }

    int gk[4], segk[4];
#pragma unroll
    for (int kf = 0; kf < 4; kf++) {
      gk[kf] = n * 128 - 128 + kbase + kf * 16 + lr;
      segk[kf] = (gk[kf] >= 0) ? segof_(gk[kf], sl, ns) : -1;
    }
#pragma unroll
    for (int m = 0; m < 2; m++)
#pragma unroll
      for (int rr = 0; rr < 4; rr++) {
        int row = w * 32 + m * 16 + lg * 4 + rr;
#pragma unroll
        for (int kf = 0; kf < 4; kf++) {
          int ki = kbase + kf * 16 + lr;
          bool valid = (gk[kf] >= 0) && (ki >= row) && (ki <= row + 128) &&
                       (segk[kf] == segq[m][rr]);
          float sv = sf[m][kf][rr];
          sf[m][kf][rr] = valid ? sv * ATTN_SCALE : -1e30f;
        }
      }

#pragma unroll
    for (int m = 0; m < 2; m++)
#pragma unroll
      for (int rr = 0; rr < 4; rr++) {
        float mx = fmaxf(fmaxf(sf[m][0][rr], sf[m][1][rr]), fmaxf(sf[m][2][rr], sf[m][3][rr]));
#pragma unroll
        for (int off = 8; off; off >>= 1) mx = fmaxf(mx, __shfl_xor(mx, off));
        float mnew = fmaxf(mr[m][rr], mx);
        float corr = __expf(mr[m][rr] - mnew);
        float ls = 0.0f;
#pragma unroll
        for (int kf = 0; kf < 4; kf++) {
          float sv = sf[m][kf][rr];
          float p = (sv <= -1e29f) ? 0.0f : __expf(sv - mnew);
          sf[m][kf][rr] = p;
          ls += p;
        }
#pragma unroll
        for (int off = 8; off; off >>= 1) ls += __shfl_xor(ls, off);
        lsum[m][rr] = lsum[m][rr] * corr + ls;
        mr[m][rr] = mnew;
#pragma unroll
        for (int nf = 0; nf < 8; nf++) o[m][nf][rr] *= corr;
      }

#pragma unroll
    for (int m = 0; m < 2; m++)
#pragma unroll
      for (int kf = 0; kf < 4; kf++)
#pragma unroll
        for (int rr = 0; rr < 4; rr++)
          p_lds[w][m * 16 + lg * 4 + rr][kf * 16 + lr] = (__bf16)sf[m][kf][rr];

#pragma unroll
    for (int s2 = 0; s2 < 2; s2++) {
      bfx8 af[2];
#pragma unroll
      for (int m = 0; m < 2; m++) af[m] = *(const bfx8*)&p_lds[w][m * 16 + lr][s2 * 32 + ko];
      int keyg = n * 128 - 128 + kbase + s2 * 32 + ko;
#pragma unroll
      for (int nf = 0; nf < 8; nf++) {
        bfx8 bfr = *(const bfx8*)&vT[(size_t)(h * HD + nf * 16 + lr) * TSEQ + keyg];
#pragma unroll
        for (int m = 0; m < 2; m++)
          o[m][nf] = __builtin_amdgcn_mfma_f32_16x16x32_bf16(af[m], bfr, o[m][nf], 0, 0, 0);
      }
    }
  }

#pragma unroll
  for (int m = 0; m < 2; m++)
#pragma unroll
    for (int rr = 0; rr < 4; rr++) {
      int gq = q0r + m * 16 + lg * 4 + rr;
      float sc = (1.0f / lsum[m][rr]) * ag[(size_t)gq * NHEAD + h];
#pragma unroll
      for (int nf = 0; nf < 8; nf++)
        yb[(size_t)gq * DIMM + h * HD + nf * 16 + lr] = (__bf16)(o[m][nf][rr] * sc);
    }
}

// ---------------- launch ----------------
extern "C" void kernel_launch(void* const* d_in, const int* in_sizes, int n_in,
                              void* d_out, int out_size, void* d_ws, size_t ws_size,
                              hipStream_t stream) {
  const float* x   = (const float*)d_in[0];
  const float* qw  = (const float*)d_in[1];
  const float* ve  = (const float*)d_in[2];
  const float* lam = (const float*)d_in[3];
  const float* f1  = (const float*)d_in[4];
  const float* f2  = (const float*)d_in[5];
  const float* agw = (const float*)d_in[6];
  const float* vgw = (const float*)d_in[7];
  const int*   sl  = (const int*)d_in[8];
  const int    ns  = in_sizes[8];
  const int*   koff = (const int*)d_in[10];
  float* out = (float*)d_out;
  char* ws = (char*)d_ws;

  const size_t MB = 1024 * 1024;
  if (ws_size < 105 * MB) return;
  __bf16* xb   = (__bf16*)(ws);
  __bf16* w1b  = (__bf16*)(ws + 16 * MB);
  __bf16* w2b  = (__bf16*)(ws + 22 * MB);
  __bf16* qkvb = (__bf16*)(ws + 24 * MB);
  __bf16* qbuf = (__bf16*)(ws + 72 * MB);
  __bf16* kbuf = (__bf16*)(ws + 88 * MB);
  float*  ag   = (float*)(ws + 104 * MB);
  __bf16* vT   = xb;    // xb dead after GEMM1
  __bf16* ybuf = qkvb;  // qkvb dead after k_qk/k_vgate

  k_conv_x<<<2048, 256, 0, stream>>>((const float4*)x, (bfx4*)xb, TSEQ * DIMM / 4);
  k_conv_w<<<1024, 256, 0, stream>>>((const float4*)qw, lam, (bfx4*)w1b, (bfx4*)w2b);
  k_gemm8p<256, 256, __bf16><<<dim3(TSEQ / 256, 3 * DIMM / 256), 512, 0, stream>>>(
      xb, w1b, qkvb, TSEQ, 3 * DIMM, DIMM);
  k_qk<<<TSEQ, 512, 0, stream>>>(qkvb, f1, f2, koff, qbuf, kbuf);
  k_vgate<<<dim3(TSEQ / 64, 2), 512, 0, stream>>>(qkvb, x, ve, agw, vgw, vT, ag);
  k_attn<<<dim3(TSEQ / 128, NHEAD), 256, 0, stream>>>(qbuf, kbuf, vT, ag, sl, ns, ybuf);
  k_gemm8p<256, 128, float><<<dim3(TSEQ / 256, DIMM / 128), 512, 0, stream>>>(
      ybuf, w2b, out, TSEQ, DIMM, DIMM);
}

// Round 5
// 183.007 us; speedup vs baseline: 1.3320x; 1.0717x over previous
//
#include <hip/hip_runtime.h>

// Fused attention block for MI355X (gfx950).
// Pipeline: conv(x,W) -> GEMM1(qkv) -> k_qk(RMS/RoPE/shift) + k_vgate(gates,vT) ->
//           windowed flash attention (S^T single-pass) -> GEMM2 -> d_out (f32)

#define TSEQ 8192
#define DIMM 1024
#define NHEAD 8
#define HD 128
#define ATTN_SCALE 0.1f
#define RMS_EPS 1.1920929e-07f

typedef __bf16 bfx2 __attribute__((ext_vector_type(2)));
typedef __bf16 bfx4 __attribute__((ext_vector_type(4)));
typedef __bf16 bfx8 __attribute__((ext_vector_type(8)));
typedef float f32x4 __attribute__((ext_vector_type(4)));
typedef short s16x4 __attribute__((ext_vector_type(4)));

#define GLDS16(g, l)                                                         \
  __builtin_amdgcn_global_load_lds(                                          \
      (const __attribute__((address_space(1))) void*)(g),                    \
      (__attribute__((address_space(3))) void*)(l), 16, 0, 0)

__device__ __forceinline__ float sig_(float z) { return 1.0f / (1.0f + __expf(-z)); }

// ---------------- f32 -> bf16 conversions ----------------
__global__ void k_conv_x(const float4* __restrict__ x, bfx4* __restrict__ xb, int n4) {
  int i = blockIdx.x * blockDim.x + threadIdx.x;
  int stride = gridDim.x * blockDim.x;
  for (; i < n4; i += stride) {
    float4 v = x[i];
    bfx4 o;
    o[0] = (__bf16)v.x; o[1] = (__bf16)v.y; o[2] = (__bf16)v.z; o[3] = (__bf16)v.w;
    xb[i] = o;
  }
}

__global__ void k_conv_w(const float4* __restrict__ w, const float* __restrict__ lam,
                         bfx4* __restrict__ w1b, bfx4* __restrict__ w2b) {
  const int n4 = 4096 * 1024 / 4;
  const float l0 = lam[0], l1 = lam[1];
  int i = blockIdx.x * blockDim.x + threadIdx.x;
  int stride = gridDim.x * blockDim.x;
  for (; i < n4; i += stride) {
    int row = (i * 4) >> 10;
    float s = (row < 3 * DIMM) ? l0 : l1;
    float4 v = w[i];
    bfx4 o;
    o[0] = (__bf16)(s * v.x); o[1] = (__bf16)(s * v.y);
    o[2] = (__bf16)(s * v.z); o[3] = (__bf16)(s * v.w);
    if (row < 3 * DIMM) w1b[i] = o;
    else                w2b[i - 3 * DIMM * DIMM / 4] = o;
  }
}

// ---------------- 8-phase pipelined GEMM: C[M,N] = A[M,K] * B[N,K]^T ----------------
template <int BM, int BN, typename CT>
__global__ __launch_bounds__(512, 2) void k_gemm8p(const __bf16* __restrict__ A,
                                                   const __bf16* __restrict__ B,
                                                   CT* __restrict__ C,
                                                   int M, int N, int K) {
  constexpr int MF = BM / 32, NF = BN / 64;
  constexpr int MH = MF / 2, NH = NF / 2;
  constexpr int LA = BM / 128, LB = BN / 128;
  __shared__ __bf16 lds[2][(BM + BN) * 64];

  const int tid = threadIdx.x;
  const int wave = tid >> 6, lane = tid & 63;
  const int wm = wave >> 2, wn = wave & 3;
  const int lr = lane & 15, lg = lane >> 4;

  const int bm = blockIdx.x, bn = blockIdx.y;

  const int srow = tid >> 3;
  const int scol = ((tid & 7) ^ (srow & 7)) * 8;
  const __bf16* Ag = A + (size_t)(bm * BM + srow) * K + scol;
  const __bf16* Bg = B + (size_t)(bn * BN + srow) * K + scol;

  char* lds0 = (char*)&lds[0][0];
  char* lds1 = (char*)&lds[1][0];

  auto stageA = [&](int kt, int hf, char* buf) {
#pragma unroll
    for (int L = 0; L < LA; L++)
      GLDS16(Ag + (size_t)(hf * (BM / 2) + L * 64) * K + kt * 64,
             buf + hf * (BM / 2) * 128 + L * 8192 + wave * 1024);
  };
  auto stageB = [&](int kt, int hf, char* buf) {
#pragma unroll
    for (int L = 0; L < LB; L++)
      GLDS16(Bg + (size_t)(hf * (BN / 2) + L * 64) * K + kt * 64,
             buf + BM * 128 + hf * (BN / 2) * 128 + L * 8192 + wave * 1024);
  };

  const int aoffs = (wm * (BM / 2) + lr) * 128;
  const int boffs = BM * 128 + (wn * (BN / 4) + lr) * 128;
  const int s0 = (lg ^ (lr & 7)) * 16;
  const int s1 = ((4 + lg) ^ (lr & 7)) * 16;

  f32x4 acc[MF][NF] = {};
  bfx8 af[MH][2], bfr[NF][2];

  auto readA = [&](char* buf, int hf) {
#pragma unroll
    for (int i = 0; i < MH; i++) {
      const char* p = buf + aoffs + (hf * MH + i) * 2048;
      af[i][0] = *(const bfx8*)(p + s0);
      af[i][1] = *(const bfx8*)(p + s1);
    }
  };
  auto readB = [&](char* buf, int hb) {
#pragma unroll
    for (int i = 0; i < NH; i++) {
      const char* p = buf + boffs + (hb * NH + i) * 2048;
      bfr[hb * NH + i][0] = *(const bfx8*)(p + s0);
      bfr[hb * NH + i][1] = *(const bfx8*)(p + s1);
    }
  };
  auto mmaQ = [&](int ha, int hb) {
    __builtin_amdgcn_s_setprio(1);
#pragma unroll
    for (int i = 0; i < MH; i++)
#pragma unroll
      for (int jq = 0; jq < NH; jq++)
#pragma unroll
        for (int kk = 0; kk < 2; kk++)
          acc[ha * MH + i][hb * NH + jq] = __builtin_amdgcn_mfma_f32_16x16x32_bf16(
              af[i][kk], bfr[hb * NH + jq][kk], acc[ha * MH + i][hb * NH + jq], 0, 0, 0);
    __builtin_amdgcn_s_setprio(0);
  };

#define BAR() __builtin_amdgcn_s_barrier()
#define LGKM0() asm volatile("s_waitcnt lgkmcnt(0)" ::: "memory")

  stageA(0, 0, lds0); stageA(0, 1, lds0); stageB(0, 0, lds0); stageB(0, 1, lds0);
  stageA(1, 0, lds1);
  asm volatile("s_waitcnt vmcnt(%0)" ::"i"(LA) : "memory");
  BAR();

  const int NT2 = K / 128;
  for (int j = 0; j < NT2; j++) {
    const bool more = (j + 1 < NT2);
    const int t1 = 2 * j + 1;
    readA(lds0, 0); readB(lds0, 0);
    stageA(t1, 1, lds1);
    BAR(); LGKM0(); mmaQ(0, 0); BAR();
    readB(lds0, 1);
    stageB(t1, 0, lds1);
    BAR(); LGKM0(); mmaQ(0, 1); BAR();
    readA(lds0, 1);
    stageB(t1, 1, lds1);
    BAR(); LGKM0(); mmaQ(1, 0); BAR();
    if (more) stageA(t1 + 1, 0, lds0);
    BAR(); LGKM0(); mmaQ(1, 1);
    if (more) { asm volatile("s_waitcnt vmcnt(%0)" ::"i"(LA) : "memory"); }
    else      { asm volatile("s_waitcnt vmcnt(0)" ::: "memory"); }
    BAR();
    readA(lds1, 0); readB(lds1, 0);
    if (more) stageA(t1 + 1, 1, lds0);
    BAR(); LGKM0(); mmaQ(0, 0); BAR();
    readB(lds1, 1);
    if (more) stageB(t1 + 1, 0, lds0);
    BAR(); LGKM0(); mmaQ(0, 1); BAR();
    readA(lds1, 1);
    if (more) stageB(t1 + 1, 1, lds0);
    BAR(); LGKM0(); mmaQ(1, 0); BAR();
    if (more) stageA(t1 + 2, 0, lds1);
    BAR(); LGKM0(); mmaQ(1, 1);
    if (more) { asm volatile("s_waitcnt vmcnt(%0)" ::"i"(LA) : "memory"); }
    else      { asm volatile("s_waitcnt vmcnt(0)" ::: "memory"); }
    BAR();
  }

  const int rbase = bm * BM + wm * (BM / 2) + lg * 4;
  const int cbase = bn * BN + wn * (BN / 4) + lr;
#pragma unroll
  for (int f = 0; f < MF; f++)
#pragma unroll
    for (int rr = 0; rr < 4; rr++) {
      size_t rowoff = (size_t)(rbase + f * 16 + rr) * N + cbase;
#pragma unroll
      for (int nf = 0; nf < NF; nf++) C[rowoff + nf * 16] = (CT)acc[f][nf][rr];
    }
#undef BAR
#undef LGKM0
}

// ---------------- q/k postprocess: RMS, RoPE, key-offset ----------------
__global__ __launch_bounds__(512) void k_qk(
    const __bf16* __restrict__ qkv, const float* __restrict__ f1,
    const float* __restrict__ f2, const int* __restrict__ koff_p,
    __bf16* __restrict__ qb, __bf16* __restrict__ kb) {
  const int t = blockIdx.x;
  const int h = threadIdx.x >> 6;
  const int l = threadIdx.x & 63;
  const int d0 = 2 * l;
  const size_t qoff = (size_t)t * (3 * DIMM) + h * HD;

  bfx2 qv = *(const bfx2*)&qkv[qoff + d0];
  bfx2 kv = *(const bfx2*)&qkv[qoff + DIMM + d0];
  float q0 = (float)qv[0], q1 = (float)qv[1];
  float k0 = (float)kv[0], k1 = (float)kv[1];

  float sq = q0 * q0 + q1 * q1;
  float sk = k0 * k0 + k1 * k1;
#pragma unroll
  for (int off = 32; off; off >>= 1) {
    sq += __shfl_xor(sq, off);
    sk += __shfl_xor(sk, off);
  }
  float rq = rsqrtf(sq * (1.0f / 128.0f) + RMS_EPS);
  float rk = rsqrtf(sk * (1.0f / 128.0f) + RMS_EPS);
  q0 *= rq; q1 *= rq; k0 *= rk; k1 *= rk;

  float2 cc = *(const float2*)&f1[(size_t)t * HD + d0];
  float2 ss = *(const float2*)&f2[(size_t)t * HD + d0];
  float rq0 = cc.x * q0 + ss.x * q1, rq1 = cc.y * q1 + ss.y * q0;
  float rk0 = cc.x * k0 + ss.x * k1, rk1 = cc.y * k1 + ss.y * k0;

  bfx2 qo; qo[0] = (__bf16)rq0; qo[1] = (__bf16)rq1;
  *(bfx2*)&qb[(size_t)t * DIMM + h * HD + d0] = qo;

  bfx2 ko2; ko2[0] = (__bf16)rk0; ko2[1] = (__bf16)rk1;
  const int koff = *koff_p;
  const size_t kcol = (size_t)h * HD + d0;
  if (!koff || l < 32) {
    *(bfx2*)&kb[(size_t)t * DIMM + kcol] = ko2;
  } else {
    if (t + 1 < TSEQ) *(bfx2*)&kb[(size_t)(t + 1) * DIMM + kcol] = ko2;
    if (t == 0)       *(bfx2*)&kb[kcol] = ko2;
  }
}

// ---------------- v postprocess: gates + ve-gate + LDS-tiled transpose ----------------
__global__ __launch_bounds__(512) void k_vgate(
    const __bf16* __restrict__ qkv, const float* __restrict__ x,
    const float* __restrict__ ve, const float* __restrict__ agw,
    const float* __restrict__ vgw, __bf16* __restrict__ vT,
    float* __restrict__ ag) {
  __shared__ float vg_lds[64][4];
  __shared__ __bf16 vtile[HD][68];
  const int t0 = blockIdx.x * 64;
  const int hbase = blockIdx.y * 4;
  const int tid = threadIdx.x;

  if (tid < 256) {
    const int tl = tid >> 2, hh = tid & 3;
    const int h = hbase + hh;
    const int t = t0 + tl;
    float za = 0.0f, zg = 0.0f;
#pragma unroll
    for (int j = 0; j < 12; j++) {
      float xv = x[(size_t)t * DIMM + j];
      za += xv * agw[h * 12 + j];
      zg += xv * vgw[h * 12 + j];
    }
    ag[(size_t)t * NHEAD + h] = sig_(za);
    vg_lds[tl][hh] = 2.0f * sig_(zg);
  }
  __syncthreads();

  const int w = tid >> 6, l = tid & 63;
  const int dout = tid >> 2, tof = (tid & 3) * 16;
  for (int hh = 0; hh < 4; hh++) {
    const int h = hbase + hh;
#pragma unroll
    for (int it = 0; it < 8; it++) {
      const int tl = w * 8 + it;
      const int t = t0 + tl;
      const size_t voff = (size_t)t * (3 * DIMM) + 2 * DIMM + h * HD;
      float va = (float)qkv[voff + l];
      float vb = (float)qkv[voff + l + 64];
      float vea = ve[(size_t)t * DIMM + h * HD + l];
      float veb = ve[(size_t)t * DIMM + h * HD + l + 64];
      float gv = vg_lds[tl][hh];
      vtile[l][tl]      = (__bf16)(va + gv * vea);
      vtile[l + 64][tl] = (__bf16)(vb + gv * veb);
    }
    __syncthreads();
    {
      bfx4 a0 = *(const bfx4*)&vtile[dout][tof];
      bfx4 a1 = *(const bfx4*)&vtile[dout][tof + 4];
      bfx4 a2 = *(const bfx4*)&vtile[dout][tof + 8];
      bfx4 a3 = *(const bfx4*)&vtile[dout][tof + 12];
      bfx8 p0, p1;
      p0[0]=a0[0]; p0[1]=a0[1]; p0[2]=a0[2]; p0[3]=a0[3];
      p0[4]=a1[0]; p0[5]=a1[1]; p0[6]=a1[2]; p0[7]=a1[3];
      p1[0]=a2[0]; p1[1]=a2[1]; p1[2]=a2[2]; p1[3]=a2[3];
      p1[4]=a3[0]; p1[5]=a3[1]; p1[6]=a3[2]; p1[7]=a3[3];
      __bf16* dst = &vT[(size_t)(h * HD + dout) * TSEQ + t0 + tof];
      *(bfx8*)dst = p0;
      *(bfx8*)(dst + 8) = p1;
    }
    __syncthreads();
  }
}

// ---------------- windowed varlen flash attention, S^T single-pass ----------------
// grid (TSEQ/64, NHEAD), 256 threads; wave w owns q rows [(bx*4+w)*16, +16).
// S^T = mfma(K,Q): lane (lr,lg) holds P[q=q0r+lr][k=kbase+16kf+4lg+rr].
// PV as O^T = mfma_16x16x16(V^T, P^T): B-frag k-slice 4lg+j == C-layout rows. No LDS.
__global__ __launch_bounds__(256, 4) void k_attn2(
    const __bf16* __restrict__ qb, const __bf16* __restrict__ kb,
    const __bf16* __restrict__ vT, const float* __restrict__ ag,
    const int* __restrict__ sl, int ns, __bf16* __restrict__ yb) {
  const int h = blockIdx.y;
  const int w = threadIdx.x >> 6, l = threadIdx.x & 63;
  const int lr = l & 15, lg = l >> 4;
  const int q0r = (blockIdx.x * 4 + w) * 16;
  const int kbase = q0r - 128;
  const int q = q0r + lr;
  // leading fully-negative key frags (uniform per wave)
  const int kfs = (q0r < 128) ? ((128 - q0r) >> 4) : 0;

  // Q B-frags (lane col = q), 4 d-steps of 32
  bfx8 qf[4];
#pragma unroll
  for (int ds = 0; ds < 4; ds++)
    qf[ds] = *(const bfx8*)&qb[(size_t)q * DIMM + h * HD + ds * 32 + lg * 8];

  // per-lane mask threshold: valid iff klo <= k <= q
  int segs = 0;
  for (int i = 0; i < ns; i++) {
    int v = sl[i];
    segs = (v <= q) ? ((v > segs) ? v : segs) : segs;
  }
  int klo = q - 128;
  if (segs > klo) klo = segs;
  if (klo < 0) klo = 0;

  // S^T = K Q^T over the 144-key window
  f32x4 sf[9] = {};
#pragma unroll
  for (int kf = 0; kf < 9; kf++) {
    if (kf >= kfs) {
      const int krow = kbase + kf * 16 + lr;
      const __bf16* kp = &kb[(size_t)krow * DIMM + h * HD + lg * 8];
      bfx8 k0 = *(const bfx8*)(kp);
      bfx8 k1 = *(const bfx8*)(kp + 32);
      bfx8 k2 = *(const bfx8*)(kp + 64);
      bfx8 k3 = *(const bfx8*)(kp + 96);
      sf[kf] = __builtin_amdgcn_mfma_f32_16x16x32_bf16(k0, qf[0], sf[kf], 0, 0, 0);
      sf[kf] = __builtin_amdgcn_mfma_f32_16x16x32_bf16(k1, qf[1], sf[kf], 0, 0, 0);
      sf[kf] = __builtin_amdgcn_mfma_f32_16x16x32_bf16(k2, qf[2], sf[kf], 0, 0, 0);
      sf[kf] = __builtin_amdgcn_mfma_f32_16x16x32_bf16(k3, qf[3], sf[kf], 0, 0, 0);
    }
  }

  // mask + scale
#pragma unroll
  for (int kf = 0; kf < 9; kf++)
#pragma unroll
    for (int rr = 0; rr < 4; rr++) {
      int k = kbase + kf * 16 + lg * 4 + rr;
      bool valid = (k >= klo) && (k <= q);
      sf[kf][rr] = valid ? sf[kf][rr] * ATTN_SCALE : -1e30f;
    }

  // row max (keys spread over kf, rr locally and lg across lanes)
  float mx = -1e30f;
#pragma unroll
  for (int kf = 0; kf < 9; kf++)
#pragma unroll
    for (int rr = 0; rr < 4; rr++) mx = fmaxf(mx, sf[kf][rr]);
  mx = fmaxf(mx, __shfl_xor(mx, 16));
  mx = fmaxf(mx, __shfl_xor(mx, 32));

  // exp + row sum
  float lsum = 0.0f;
#pragma unroll
  for (int kf = 0; kf < 9; kf++)
#pragma unroll
    for (int rr = 0; rr < 4; rr++) {
      float p = __expf(sf[kf][rr] - mx);
      sf[kf][rr] = p;
      lsum += p;
    }
  lsum += __shfl_xor(lsum, 16);
  lsum += __shfl_xor(lsum, 32);

  // O^T = V^T P^T via 16x16x16 MFMAs; P^T B-frag = direct bf16 pack of sf regs
  f32x4 o[8] = {};
#pragma unroll
  for (int kf = 0; kf < 9; kf++) {
    if (kf >= kfs) {
      bfx4 pc;
      pc[0] = (__bf16)sf[kf][0]; pc[1] = (__bf16)sf[kf][1];
      pc[2] = (__bf16)sf[kf][2]; pc[3] = (__bf16)sf[kf][3];
      s16x4 pb = *(s16x4*)&pc;
      const int kk = kbase + kf * 16 + 4 * lg;
#pragma unroll
      for (int nf = 0; nf < 8; nf++) {
        s16x4 vf = *(const s16x4*)&vT[(size_t)(h * HD + nf * 16 + lr) * TSEQ + kk];
        o[nf] = __builtin_amdgcn_mfma_f32_16x16x16bf16_1k(vf, pb, o[nf], 0, 0, 0);
      }
    }
  }

  // epilogue: normalize + gate; O^T lane: q=lr, d = nf*16 + lg*4 + rr
  const float sc = ag[(size_t)q * NHEAD + h] / lsum;
#pragma unroll
  for (int nf = 0; nf < 8; nf++) {
    bfx4 st;
#pragma unroll
    for (int rr = 0; rr < 4; rr++) st[rr] = (__bf16)(o[nf][rr] * sc);
    *(bfx4*)&yb[(size_t)q * DIMM + h * HD + nf * 16 + lg * 4] = st;
  }
}

// ---------------- launch ----------------
extern "C" void kernel_launch(void* const* d_in, const int* in_sizes, int n_in,
                              void* d_out, int out_size, void* d_ws, size_t ws_size,
                              hipStream_t stream) {
  const float* x   = (const float*)d_in[0];
  const float* qw  = (const float*)d_in[1];
  const float* ve  = (const float*)d_in[2];
  const float* lam = (const float*)d_in[3];
  const float* f1  = (const float*)d_in[4];
  const float* f2  = (const float*)d_in[5];
  const float* agw = (const float*)d_in[6];
  const float* vgw = (const float*)d_in[7];
  const int*   sl  = (const int*)d_in[8];
  const int    ns  = in_sizes[8];
  const int*   koff = (const int*)d_in[10];
  float* out = (float*)d_out;
  char* ws = (char*)d_ws;

  const size_t MB = 1024 * 1024;
  if (ws_size < 105 * MB) return;
  __bf16* xb   = (__bf16*)(ws);
  __bf16* w1b  = (__bf16*)(ws + 16 * MB);
  __bf16* w2b  = (__bf16*)(ws + 22 * MB);
  __bf16* qkvb = (__bf16*)(ws + 24 * MB);
  __bf16* qbuf = (__bf16*)(ws + 72 * MB);
  __bf16* kbuf = (__bf16*)(ws + 88 * MB);
  float*  ag   = (float*)(ws + 104 * MB);
  __bf16* vT   = xb;    // xb dead after GEMM1
  __bf16* ybuf = qkvb;  // qkvb dead after k_qk/k_vgate

  k_conv_x<<<2048, 256, 0, stream>>>((const float4*)x, (bfx4*)xb, TSEQ * DIMM / 4);
  k_conv_w<<<1024, 256, 0, stream>>>((const float4*)qw, lam, (bfx4*)w1b, (bfx4*)w2b);
  k_gemm8p<256, 256, __bf16><<<dim3(TSEQ / 256, 3 * DIMM / 256), 512, 0, stream>>>(
      xb, w1b, qkvb, TSEQ, 3 * DIMM, DIMM);
  k_qk<<<TSEQ, 512, 0, stream>>>(qkvb, f1, f2, koff, qbuf, kbuf);
  k_vgate<<<dim3(TSEQ / 64, 2), 512, 0, stream>>>(qkvb, x, ve, agw, vgw, vT, ag);
  k_attn2<<<dim3(TSEQ / 64, NHEAD), 256, 0, stream>>>(qbuf, kbuf, vT, ag, sl, ns, ybuf);
  k_gemm8p<256, 128, float><<<dim3(TSEQ / 256, DIMM / 128), 512, 0, stream>>>(
      ybuf, w2b, out, TSEQ, DIMM, DIMM);
}

// Round 6
// 182.949 us; speedup vs baseline: 1.3324x; 1.0003x over previous
//
#include <hip/hip_runtime.h>

// Fused attention block for MI355X (gfx950).
// Pipeline: conv(x,W) -> GEMM1(qkv) -> k_qk(RMS/RoPE/shift) + k_vgate(gates,vT) ->
//           windowed flash attention (S^T single-pass) -> GEMM2 -> d_out (f32)

#define TSEQ 8192
#define DIMM 1024
#define NHEAD 8
#define HD 128
#define ATTN_SCALE 0.1f
#define RMS_EPS 1.1920929e-07f

typedef __bf16 bfx2 __attribute__((ext_vector_type(2)));
typedef __bf16 bfx4 __attribute__((ext_vector_type(4)));
typedef __bf16 bfx8 __attribute__((ext_vector_type(8)));
typedef float f32x4 __attribute__((ext_vector_type(4)));
typedef short s16x4 __attribute__((ext_vector_type(4)));

#define GLDS16(g, l)                                                         \
  __builtin_amdgcn_global_load_lds(                                          \
      (const __attribute__((address_space(1))) void*)(g),                    \
      (__attribute__((address_space(3))) void*)(l), 16, 0, 0)

__device__ __forceinline__ float sig_(float z) { return 1.0f / (1.0f + __expf(-z)); }

// ---------------- f32 -> bf16 conversions ----------------
__global__ void k_conv_x(const float4* __restrict__ x, bfx4* __restrict__ xb, int n4) {
  int i = blockIdx.x * blockDim.x + threadIdx.x;
  int stride = gridDim.x * blockDim.x;
  for (; i < n4; i += stride) {
    float4 v = x[i];
    bfx4 o;
    o[0] = (__bf16)v.x; o[1] = (__bf16)v.y; o[2] = (__bf16)v.z; o[3] = (__bf16)v.w;
    xb[i] = o;
  }
}

__global__ void k_conv_w(const float4* __restrict__ w, const float* __restrict__ lam,
                         bfx4* __restrict__ w1b, bfx4* __restrict__ w2b) {
  const int n4 = 4096 * 1024 / 4;
  const float l0 = lam[0], l1 = lam[1];
  int i = blockIdx.x * blockDim.x + threadIdx.x;
  int stride = gridDim.x * blockDim.x;
  for (; i < n4; i += stride) {
    int row = (i * 4) >> 10;
    float s = (row < 3 * DIMM) ? l0 : l1;
    float4 v = w[i];
    bfx4 o;
    o[0] = (__bf16)(s * v.x); o[1] = (__bf16)(s * v.y);
    o[2] = (__bf16)(s * v.z); o[3] = (__bf16)(s * v.w);
    if (row < 3 * DIMM) w1b[i] = o;
    else                w2b[i - 3 * DIMM * DIMM / 4] = o;
  }
}

// ---------------- 8-phase pipelined GEMM: C[M,N] = A[M,K] * B[N,K]^T ----------------
// Consumption-ordered staging: each half-tile staged exactly 4-5 phases before its
// first ds_read; per-phase counted vmcnt (N1/N2, never 0 in steady state).
// Stage slots per iter (2 K-tiles t0->buf0, t1->buf1):
//   ph0:Blo(t1) ph1:Bhi(t1) ph2:Ahi(t1) ph3:Alo(t1+1) ph4:Blo(t1+1) ph5:Bhi(t1+1)
//   ph6:Ahi(t1+1) ph7:Alo(t1+2)        (Alo(t1) staged at prev ph7)
// Reads: ph0:{Alo,Blo}b0 ph1:{Bhi}b0 ph2:{Ahi}b0 ph4:{Alo,Blo}b1 ph5:{Bhi}b1 ph6:{Ahi}b1
template <int BM, int BN, typename CT>
__global__ __launch_bounds__(512, 2) void k_gemm8p(const __bf16* __restrict__ A,
                                                   const __bf16* __restrict__ B,
                                                   CT* __restrict__ C,
                                                   int M, int N, int K) {
  constexpr int MF = BM / 32, NF = BN / 64;
  constexpr int MH = MF / 2, NH = NF / 2;
  constexpr int LA = BM / 128, LB = BN / 128;   // loads per half-tile stage
  constexpr int N1 = 2 * LA + LB;               // wait count (ph7/0/3/4 ends)
  constexpr int N2 = LA + 2 * LB;               // wait count (ph1/5 ends)
  __shared__ __bf16 lds[2][(BM + BN) * 64];

  const int tid = threadIdx.x;
  const int wave = tid >> 6, lane = tid & 63;
  const int wm = wave >> 2, wn = wave & 3;
  const int lr = lane & 15, lg = lane >> 4;

  const int bm = blockIdx.x, bn = blockIdx.y;

  const int srow = tid >> 3;
  const int scol = ((tid & 7) ^ (srow & 7)) * 8;
  const __bf16* Ag = A + (size_t)(bm * BM + srow) * K + scol;
  const __bf16* Bg = B + (size_t)(bn * BN + srow) * K + scol;

  char* lds0 = (char*)&lds[0][0];
  char* lds1 = (char*)&lds[1][0];

  auto stageA = [&](int kt, int hf, char* buf) {
#pragma unroll
    for (int L = 0; L < LA; L++)
      GLDS16(Ag + (size_t)(hf * (BM / 2) + L * 64) * K + kt * 64,
             buf + hf * (BM / 2) * 128 + L * 8192 + wave * 1024);
  };
  auto stageB = [&](int kt, int hf, char* buf) {
#pragma unroll
    for (int L = 0; L < LB; L++)
      GLDS16(Bg + (size_t)(hf * (BN / 2) + L * 64) * K + kt * 64,
             buf + BM * 128 + hf * (BN / 2) * 128 + L * 8192 + wave * 1024);
  };

  const int aoffs = (wm * (BM / 2) + lr) * 128;
  const int boffs = BM * 128 + (wn * (BN / 4) + lr) * 128;
  const int s0 = (lg ^ (lr & 7)) * 16;
  const int s1 = ((4 + lg) ^ (lr & 7)) * 16;

  f32x4 acc[MF][NF] = {};
  bfx8 af[MH][2], bfr[NF][2];

  auto readA = [&](char* buf, int hf) {
#pragma unroll
    for (int i = 0; i < MH; i++) {
      const char* p = buf + aoffs + (hf * MH + i) * 2048;
      af[i][0] = *(const bfx8*)(p + s0);
      af[i][1] = *(const bfx8*)(p + s1);
    }
  };
  auto readB = [&](char* buf, int hb) {
#pragma unroll
    for (int i = 0; i < NH; i++) {
      const char* p = buf + boffs + (hb * NH + i) * 2048;
      bfr[hb * NH + i][0] = *(const bfx8*)(p + s0);
      bfr[hb * NH + i][1] = *(const bfx8*)(p + s1);
    }
  };
  auto mmaQ = [&](int ha, int hb) {
    __builtin_amdgcn_s_setprio(1);
#pragma unroll
    for (int i = 0; i < MH; i++)
#pragma unroll
      for (int jq = 0; jq < NH; jq++)
#pragma unroll
        for (int kk = 0; kk < 2; kk++)
          acc[ha * MH + i][hb * NH + jq] = __builtin_amdgcn_mfma_f32_16x16x32_bf16(
              af[i][kk], bfr[hb * NH + jq][kk], acc[ha * MH + i][hb * NH + jq], 0, 0, 0);
    __builtin_amdgcn_s_setprio(0);
  };

#define BAR() __builtin_amdgcn_s_barrier()
#define LGKM0() asm volatile("s_waitcnt lgkmcnt(0)" ::: "memory")
#define VMC(n) asm volatile("s_waitcnt vmcnt(%0)" ::"i"(n) : "memory")

  // prologue (consumption order): Alo0,Blo0,Bhi0,Ahi0 -> buf0; Alo1 -> buf1
  stageA(0, 0, lds0); stageB(0, 0, lds0); stageB(0, 1, lds0); stageA(0, 1, lds0);
  stageA(1, 0, lds1);
  VMC(N1); BAR();

  const int NT2 = K / 128;
  for (int j = 0; j < NT2; j++) {
    const bool more = (j + 1 < NT2);
    const int t1 = 2 * j + 1;
    // ph0: reads buf0 {Alo,Blo}; stage Blo(t1)->buf1
    readA(lds0, 0); readB(lds0, 0);
    stageB(t1, 0, lds1);
    BAR(); LGKM0(); mmaQ(0, 0); VMC(N1); BAR();
    // ph1: reads buf0 {Bhi}; stage Bhi(t1)->buf1
    readB(lds0, 1);
    stageB(t1, 1, lds1);
    BAR(); LGKM0(); mmaQ(0, 1); VMC(N2); BAR();
    // ph2: reads buf0 {Ahi}; stage Ahi(t1)->buf1
    readA(lds0, 1);
    stageA(t1, 1, lds1);
    BAR(); LGKM0(); mmaQ(1, 0); BAR();
    // ph3: stage Alo(t1+1)->buf0
    if (more) stageA(t1 + 1, 0, lds0);
    BAR(); LGKM0(); mmaQ(1, 1);
    if (more) { VMC(N1); } else { VMC(LA + LB); }
    BAR();
    // ph4: reads buf1 {Alo,Blo}; stage Blo(t1+1)->buf0
    readA(lds1, 0); readB(lds1, 0);
    if (more) stageB(t1 + 1, 0, lds0);
    BAR(); LGKM0(); mmaQ(0, 0);
    if (more) { VMC(N1); } else { VMC(LA); }
    BAR();
    // ph5: reads buf1 {Bhi}; stage Bhi(t1+1)->buf0
    readB(lds1, 1);
    if (more) stageB(t1 + 1, 1, lds0);
    BAR(); LGKM0(); mmaQ(0, 1);
    if (more) { VMC(N2); } else { VMC(0); }
    BAR();
    // ph6: reads buf1 {Ahi}; stage Ahi(t1+1)->buf0
    readA(lds1, 1);
    if (more) stageA(t1 + 1, 1, lds0);
    BAR(); LGKM0(); mmaQ(1, 0); BAR();
    // ph7: stage Alo(t1+2)->buf1
    if (more) stageA(t1 + 2, 0, lds1);
    BAR(); LGKM0(); mmaQ(1, 1);
    if (more) { VMC(N1); }
    BAR();
  }

  const int rbase = bm * BM + wm * (BM / 2) + lg * 4;
  const int cbase = bn * BN + wn * (BN / 4) + lr;
#pragma unroll
  for (int f = 0; f < MF; f++)
#pragma unroll
    for (int rr = 0; rr < 4; rr++) {
      size_t rowoff = (size_t)(rbase + f * 16 + rr) * N + cbase;
#pragma unroll
      for (int nf = 0; nf < NF; nf++) C[rowoff + nf * 16] = (CT)acc[f][nf][rr];
    }
#undef BAR
#undef LGKM0
#undef VMC
}

// ---------------- q/k postprocess: RMS, RoPE, key-offset ----------------
__global__ __launch_bounds__(512) void k_qk(
    const __bf16* __restrict__ qkv, const float* __restrict__ f1,
    const float* __restrict__ f2, const int* __restrict__ koff_p,
    __bf16* __restrict__ qb, __bf16* __restrict__ kb) {
  const int t = blockIdx.x;
  const int h = threadIdx.x >> 6;
  const int l = threadIdx.x & 63;
  const int d0 = 2 * l;
  const size_t qoff = (size_t)t * (3 * DIMM) + h * HD;

  bfx2 qv = *(const bfx2*)&qkv[qoff + d0];
  bfx2 kv = *(const bfx2*)&qkv[qoff + DIMM + d0];
  float q0 = (float)qv[0], q1 = (float)qv[1];
  float k0 = (float)kv[0], k1 = (float)kv[1];

  float sq = q0 * q0 + q1 * q1;
  float sk = k0 * k0 + k1 * k1;
#pragma unroll
  for (int off = 32; off; off >>= 1) {
    sq += __shfl_xor(sq, off);
    sk += __shfl_xor(sk, off);
  }
  float rq = rsqrtf(sq * (1.0f / 128.0f) + RMS_EPS);
  float rk = rsqrtf(sk * (1.0f / 128.0f) + RMS_EPS);
  q0 *= rq; q1 *= rq; k0 *= rk; k1 *= rk;

  float2 cc = *(const float2*)&f1[(size_t)t * HD + d0];
  float2 ss = *(const float2*)&f2[(size_t)t * HD + d0];
  float rq0 = cc.x * q0 + ss.x * q1, rq1 = cc.y * q1 + ss.y * q0;
  float rk0 = cc.x * k0 + ss.x * k1, rk1 = cc.y * k1 + ss.y * k0;

  bfx2 qo; qo[0] = (__bf16)rq0; qo[1] = (__bf16)rq1;
  *(bfx2*)&qb[(size_t)t * DIMM + h * HD + d0] = qo;

  bfx2 ko2; ko2[0] = (__bf16)rk0; ko2[1] = (__bf16)rk1;
  const int koff = *koff_p;
  const size_t kcol = (size_t)h * HD + d0;
  if (!koff || l < 32) {
    *(bfx2*)&kb[(size_t)t * DIMM + kcol] = ko2;
  } else {
    if (t + 1 < TSEQ) *(bfx2*)&kb[(size_t)(t + 1) * DIMM + kcol] = ko2;
    if (t == 0)       *(bfx2*)&kb[kcol] = ko2;
  }
}

// ---------------- v postprocess: gates + ve-gate + LDS-tiled transpose ----------------
__global__ __launch_bounds__(512) void k_vgate(
    const __bf16* __restrict__ qkv, const float* __restrict__ x,
    const float* __restrict__ ve, const float* __restrict__ agw,
    const float* __restrict__ vgw, __bf16* __restrict__ vT,
    float* __restrict__ ag) {
  __shared__ float vg_lds[64][4];
  __shared__ __bf16 vtile[HD][68];
  const int t0 = blockIdx.x * 64;
  const int hbase = blockIdx.y * 4;
  const int tid = threadIdx.x;

  if (tid < 256) {
    const int tl = tid >> 2, hh = tid & 3;
    const int h = hbase + hh;
    const int t = t0 + tl;
    float za = 0.0f, zg = 0.0f;
#pragma unroll
    for (int j = 0; j < 12; j++) {
      float xv = x[(size_t)t * DIMM + j];
      za += xv * agw[h * 12 + j];
      zg += xv * vgw[h * 12 + j];
    }
    ag[(size_t)t * NHEAD + h] = sig_(za);
    vg_lds[tl][hh] = 2.0f * sig_(zg);
  }
  __syncthreads();

  const int w = tid >> 6, l = tid & 63;
  const int dout = tid >> 2, tof = (tid & 3) * 16;
  for (int hh = 0; hh < 4; hh++) {
    const int h = hbase + hh;
#pragma unroll
    for (int it = 0; it < 8; it++) {
      const int tl = w * 8 + it;
      const int t = t0 + tl;
      const size_t voff = (size_t)t * (3 * DIMM) + 2 * DIMM + h * HD;
      float va = (float)qkv[voff + l];
      float vb = (float)qkv[voff + l + 64];
      float vea = ve[(size_t)t * DIMM + h * HD + l];
      float veb = ve[(size_t)t * DIMM + h * HD + l + 64];
      float gv = vg_lds[tl][hh];
      vtile[l][tl]      = (__bf16)(va + gv * vea);
      vtile[l + 64][tl] = (__bf16)(vb + gv * veb);
    }
    __syncthreads();
    {
      bfx4 a0 = *(const bfx4*)&vtile[dout][tof];
      bfx4 a1 = *(const bfx4*)&vtile[dout][tof + 4];
      bfx4 a2 = *(const bfx4*)&vtile[dout][tof + 8];
      bfx4 a3 = *(const bfx4*)&vtile[dout][tof + 12];
      bfx8 p0, p1;
      p0[0]=a0[0]; p0[1]=a0[1]; p0[2]=a0[2]; p0[3]=a0[3];
      p0[4]=a1[0]; p0[5]=a1[1]; p0[6]=a1[2]; p0[7]=a1[3];
      p1[0]=a2[0]; p1[1]=a2[1]; p1[2]=a2[2]; p1[3]=a2[3];
      p1[4]=a3[0]; p1[5]=a3[1]; p1[6]=a3[2]; p1[7]=a3[3];
      __bf16* dst = &vT[(size_t)(h * HD + dout) * TSEQ + t0 + tof];
      *(bfx8*)dst = p0;
      *(bfx8*)(dst + 8) = p1;
    }
    __syncthreads();
  }
}

// ---------------- windowed varlen flash attention, S^T single-pass ----------------
__global__ __launch_bounds__(256, 4) void k_attn2(
    const __bf16* __restrict__ qb, const __bf16* __restrict__ kb,
    const __bf16* __restrict__ vT, const float* __restrict__ ag,
    const int* __restrict__ sl, int ns, __bf16* __restrict__ yb) {
  const int h = blockIdx.y;
  const int w = threadIdx.x >> 6, l = threadIdx.x & 63;
  const int lr = l & 15, lg = l >> 4;
  const int q0r = (blockIdx.x * 4 + w) * 16;
  const int kbase = q0r - 128;
  const int q = q0r + lr;
  const int kfs = (q0r < 128) ? ((128 - q0r) >> 4) : 0;

  bfx8 qf[4];
#pragma unroll
  for (int ds = 0; ds < 4; ds++)
    qf[ds] = *(const bfx8*)&qb[(size_t)q * DIMM + h * HD + ds * 32 + lg * 8];

  int segs = 0;
  for (int i = 0; i < ns; i++) {
    int v = sl[i];
    segs = (v <= q) ? ((v > segs) ? v : segs) : segs;
  }
  int klo = q - 128;
  if (segs > klo) klo = segs;
  if (klo < 0) klo = 0;

  f32x4 sf[9] = {};
#pragma unroll
  for (int kf = 0; kf < 9; kf++) {
    if (kf >= kfs) {
      const int krow = kbase + kf * 16 + lr;
      const __bf16* kp = &kb[(size_t)krow * DIMM + h * HD + lg * 8];
      bfx8 k0 = *(const bfx8*)(kp);
      bfx8 k1 = *(const bfx8*)(kp + 32);
      bfx8 k2 = *(const bfx8*)(kp + 64);
      bfx8 k3 = *(const bfx8*)(kp + 96);
      sf[kf] = __builtin_amdgcn_mfma_f32_16x16x32_bf16(k0, qf[0], sf[kf], 0, 0, 0);
      sf[kf] = __builtin_amdgcn_mfma_f32_16x16x32_bf16(k1, qf[1], sf[kf], 0, 0, 0);
      sf[kf] = __builtin_amdgcn_mfma_f32_16x16x32_bf16(k2, qf[2], sf[kf], 0, 0, 0);
      sf[kf] = __builtin_amdgcn_mfma_f32_16x16x32_bf16(k3, qf[3], sf[kf], 0, 0, 0);
    }
  }

#pragma unroll
  for (int kf = 0; kf < 9; kf++)
#pragma unroll
    for (int rr = 0; rr < 4; rr++) {
      int k = kbase + kf * 16 + lg * 4 + rr;
      bool valid = (k >= klo) && (k <= q);
      sf[kf][rr] = valid ? sf[kf][rr] * ATTN_SCALE : -1e30f;
    }

  float mx = -1e30f;
#pragma unroll
  for (int kf = 0; kf < 9; kf++)
#pragma unroll
    for (int rr = 0; rr < 4; rr++) mx = fmaxf(mx, sf[kf][rr]);
  mx = fmaxf(mx, __shfl_xor(mx, 16));
  mx = fmaxf(mx, __shfl_xor(mx, 32));

  float lsum = 0.0f;
#pragma unroll
  for (int kf = 0; kf < 9; kf++)
#pragma unroll
    for (int rr = 0; rr < 4; rr++) {
      float p = __expf(sf[kf][rr] - mx);
      sf[kf][rr] = p;
      lsum += p;
    }
  lsum += __shfl_xor(lsum, 16);
  lsum += __shfl_xor(lsum, 32);

  f32x4 o[8] = {};
#pragma unroll
  for (int kf = 0; kf < 9; kf++) {
    if (kf >= kfs) {
      bfx4 pc;
      pc[0] = (__bf16)sf[kf][0]; pc[1] = (__bf16)sf[kf][1];
      pc[2] = (__bf16)sf[kf][2]; pc[3] = (__bf16)sf[kf][3];
      s16x4 pb = *(s16x4*)&pc;
      const int kk = kbase + kf * 16 + 4 * lg;
#pragma unroll
      for (int nf = 0; nf < 8; nf++) {
        s16x4 vf = *(const s16x4*)&vT[(size_t)(h * HD + nf * 16 + lr) * TSEQ + kk];
        o[nf] = __builtin_amdgcn_mfma_f32_16x16x16bf16_1k(vf, pb, o[nf], 0, 0, 0);
      }
    }
  }

  const float sc = ag[(size_t)q * NHEAD + h] / lsum;
#pragma unroll
  for (int nf = 0; nf < 8; nf++) {
    bfx4 st;
#pragma unroll
    for (int rr = 0; rr < 4; rr++) st[rr] = (__bf16)(o[nf][rr] * sc);
    *(bfx4*)&yb[(size_t)q * DIMM + h * HD + nf * 16 + lg * 4] = st;
  }
}

// ---------------- launch ----------------
extern "C" void kernel_launch(void* const* d_in, const int* in_sizes, int n_in,
                              void* d_out, int out_size, void* d_ws, size_t ws_size,
                              hipStream_t stream) {
  const float* x   = (const float*)d_in[0];
  const float* qw  = (const float*)d_in[1];
  const float* ve  = (const float*)d_in[2];
  const float* lam = (const float*)d_in[3];
  const float* f1  = (const float*)d_in[4];
  const float* f2  = (const float*)d_in[5];
  const float* agw = (const float*)d_in[6];
  const float* vgw = (const float*)d_in[7];
  const int*   sl  = (const int*)d_in[8];
  const int    ns  = in_sizes[8];
  const int*   koff = (const int*)d_in[10];
  float* out = (float*)d_out;
  char* ws = (char*)d_ws;

  const size_t MB = 1024 * 1024;
  if (ws_size < 105 * MB) return;
  __bf16* xb   = (__bf16*)(ws);
  __bf16* w1b  = (__bf16*)(ws + 16 * MB);
  __bf16* w2b  = (__bf16*)(ws + 22 * MB);
  __bf16* qkvb = (__bf16*)(ws + 24 * MB);
  __bf16* qbuf = (__bf16*)(ws + 72 * MB);
  __bf16* kbuf = (__bf16*)(ws + 88 * MB);
  float*  ag   = (float*)(ws + 104 * MB);
  __bf16* vT   = xb;    // xb dead after GEMM1
  __bf16* ybuf = qkvb;  // qkvb dead after k_qk/k_vgate

  k_conv_x<<<2048, 256, 0, stream>>>((const float4*)x, (bfx4*)xb, TSEQ * DIMM / 4);
  k_conv_w<<<1024, 256, 0, stream>>>((const float4*)qw, lam, (bfx4*)w1b, (bfx4*)w2b);
  k_gemm8p<256, 256, __bf16><<<dim3(TSEQ / 256, 3 * DIMM / 256), 512, 0, stream>>>(
      xb, w1b, qkvb, TSEQ, 3 * DIMM, DIMM);
  k_qk<<<TSEQ, 512, 0, stream>>>(qkvb, f1, f2, koff, qbuf, kbuf);
  k_vgate<<<dim3(TSEQ / 64, 2), 512, 0, stream>>>(qkvb, x, ve, agw, vgw, vT, ag);
  k_attn2<<<dim3(TSEQ / 64, NHEAD), 256, 0, stream>>>(qbuf, kbuf, vT, ag, sl, ns, ybuf);
  k_gemm8p<256, 128, float><<<dim3(TSEQ / 256, DIMM / 128), 512, 0, stream>>>(
      ybuf, w2b, out, TSEQ, DIMM, DIMM);
}

// Round 7
// 180.473 us; speedup vs baseline: 1.3507x; 1.0137x over previous
//
#include <hip/hip_runtime.h>
#include <type_traits>

// Fused attention block for MI355X (gfx950).
// Pipeline: conv(x,W) -> GEMM1(qkv) -> k_qk(RMS/RoPE/shift) + k_vgate(gates,vT) ->
//           windowed flash attention (S^T single-pass) -> GEMM2 -> d_out (f32)

#define TSEQ 8192
#define DIMM 1024
#define NHEAD 8
#define HD 128
#define ATTN_SCALE 0.1f
#define RMS_EPS 1.1920929e-07f

typedef __bf16 bfx2 __attribute__((ext_vector_type(2)));
typedef __bf16 bfx4 __attribute__((ext_vector_type(4)));
typedef __bf16 bfx8 __attribute__((ext_vector_type(8)));
typedef float f32x4 __attribute__((ext_vector_type(4)));
typedef short s16x4 __attribute__((ext_vector_type(4)));

#define GLDS16(g, l)                                                         \
  __builtin_amdgcn_global_load_lds(                                          \
      (const __attribute__((address_space(1))) void*)(g),                    \
      (__attribute__((address_space(3))) void*)(l), 16, 0, 0)

__device__ __forceinline__ float sig_(float z) { return 1.0f / (1.0f + __expf(-z)); }

// ---------------- f32 -> bf16 conversions ----------------
__global__ void k_conv_x(const float4* __restrict__ x, bfx4* __restrict__ xb, int n4) {
  int i = blockIdx.x * blockDim.x + threadIdx.x;
  int stride = gridDim.x * blockDim.x;
  for (; i < n4; i += stride) {
    float4 v = x[i];
    bfx4 o;
    o[0] = (__bf16)v.x; o[1] = (__bf16)v.y; o[2] = (__bf16)v.z; o[3] = (__bf16)v.w;
    xb[i] = o;
  }
}

__global__ void k_conv_w(const float4* __restrict__ w, const float* __restrict__ lam,
                         bfx4* __restrict__ w1b, bfx4* __restrict__ w2b) {
  const int n4 = 4096 * 1024 / 4;
  const float l0 = lam[0], l1 = lam[1];
  int i = blockIdx.x * blockDim.x + threadIdx.x;
  int stride = gridDim.x * blockDim.x;
  for (; i < n4; i += stride) {
    int row = (i * 4) >> 10;
    float s = (row < 3 * DIMM) ? l0 : l1;
    float4 v = w[i];
    bfx4 o;
    o[0] = (__bf16)(s * v.x); o[1] = (__bf16)(s * v.y);
    o[2] = (__bf16)(s * v.z); o[3] = (__bf16)(s * v.w);
    if (row < 3 * DIMM) w1b[i] = o;
    else                w2b[i - 3 * DIMM * DIMM / 4] = o;
  }
}

// ---------------- interleaved 8-phase GEMM: C[M,N] = A[M,K] * B[N,K]^T ----------------
// BMx256 tile, BK=64, 8 waves (2x4), fixed buffers (lds0=even tiles, lds1=odd).
// Next-phase ds_reads interleaved INSIDE the MFMA cluster (reload a frag right after
// its last consuming MFMA), pinned via sched_group_barrier. 1 barrier/phase.
// Stage slots/iter: ph0:Au0(t1) ph1:Au1(t1) ph2:Bu0(t2) ph3:Bu1(t2) ph4:Au0(t2)
//                   ph5:Au1(t2) ph6:Bu0(t3) ph7:Bu1(t3)
// VMC: ph1-end 2LA (forces B(t1)), ph2-end LB (forces A(t1)), ph5-end 2LA (B(t2)),
//      ph6-end LB (A(t2)).  Last iter peeled (compile-time `more`).
template <int BM, typename CT>
__global__ __launch_bounds__(512, 2) void k_gemm8i(const __bf16* __restrict__ A,
                                                   const __bf16* __restrict__ B,
                                                   CT* __restrict__ C,
                                                   int M, int N, int K) {
  constexpr int BN = 256;
  constexpr int MF = BM / 32, NF = 4;
  constexpr int MH = MF / 2;
  constexpr int LA = BM / 128, LB = 2;
  __shared__ __bf16 lds0s[(BM + BN) * 64];
  __shared__ __bf16 lds1s[(BM + BN) * 64];
  char* lds0 = (char*)lds0s;
  char* lds1 = (char*)lds1s;

  const int tid = threadIdx.x;
  const int wave = tid >> 6, lane = tid & 63;
  const int wm = wave >> 2, wn = wave & 3;
  const int lr = lane & 15, lg = lane >> 4;
  const int bm = blockIdx.x, bn = blockIdx.y;

  const int srow = tid >> 3;
  const int scol = ((tid & 7) ^ (srow & 7)) * 8;  // pre-swizzled global col
  const __bf16* Ag = A + (size_t)(bm * BM + srow) * K + scol;
  const __bf16* Bg = B + (size_t)(bn * BN + srow) * K + scol;

  auto stageAu = [&](int kt, int u, char* buf) {
#pragma unroll
    for (int L = 0; L < LA; L++)
      GLDS16(Ag + (size_t)(u * (BM / 2) + L * 64) * K + kt * 64,
             buf + (u * (BM / 2) + L * 64) * 128 + wave * 1024);
  };
  auto stageBu = [&](int kt, int u, char* buf) {
#pragma unroll
    for (int L = 0; L < LB; L++)
      GLDS16(Bg + (size_t)(u * 128 + L * 64) * K + kt * 64,
             buf + BM * 128 + (u * 128 + L * 64) * 128 + wave * 1024);
  };

  const int aoffs = (wm * (BM / 2) + lr) * 128;
  const int boffs = BM * 128 + (wn * 64 + lr) * 128;
  const int s0 = (lg ^ (lr & 7)) * 16;
  const int s1 = ((4 + lg) ^ (lr & 7)) * 16;

  f32x4 acc[MF][NF] = {};
  bfx8 af[MH][2], bfr[NF][2];

  auto readAf = [&](int i, const char* rbuf, int hf) {
    const char* p = rbuf + aoffs + (hf * MH + i) * 2048;
    af[i][0] = *(const bfx8*)(p + s0);
    af[i][1] = *(const bfx8*)(p + s1);
  };
  auto readBf = [&](int f, const char* rbuf) {
    const char* p = rbuf + boffs + f * 2048;
    bfr[f][0] = *(const bfx8*)(p + s0);
    bfr[f][1] = *(const bfx8*)(p + s1);
  };
  auto mfma2 = [&](int ha, int hb, int i, int j) {
    acc[ha * MH + i][hb * 2 + j] = __builtin_amdgcn_mfma_f32_16x16x32_bf16(
        af[i][0], bfr[hb * 2 + j][0], acc[ha * MH + i][hb * 2 + j], 0, 0, 0);
    acc[ha * MH + i][hb * 2 + j] = __builtin_amdgcn_mfma_f32_16x16x32_bf16(
        af[i][1], bfr[hb * 2 + j][1], acc[ha * MH + i][hb * 2 + j], 0, 0, 0);
  };
  auto clusterPlain = [&](int ha, int hb) {
    __builtin_amdgcn_s_setprio(1);
#pragma unroll
    for (int i = 0; i < MH; i++) { mfma2(ha, hb, i, 0); mfma2(ha, hb, i, 1); }
    __builtin_amdgcn_s_setprio(0);
  };
  // MFMA cluster with A-frag reload interleaved after each frag's last use
  auto clusterA_r = [&](int ha, int hb, const char* rbuf, int hf) {
    __builtin_amdgcn_s_setprio(1);
#pragma unroll
    for (int i = 0; i < MH; i++) {
      mfma2(ha, hb, i, 0); mfma2(ha, hb, i, 1);
      readAf(i, rbuf, hf);
      __builtin_amdgcn_sched_group_barrier(0x8, 4, 0);    // 4 MFMA
      __builtin_amdgcn_sched_group_barrier(0x100, 2, 0);  // 2 DS_READ
    }
    __builtin_amdgcn_s_setprio(0);
  };
  // MFMA cluster with B-frag-pair reload interleaved
  auto clusterB_r = [&](int ha, int hb, const char* rbuf) {
    __builtin_amdgcn_s_setprio(1);
#pragma unroll
    for (int j = 0; j < 2; j++) {
#pragma unroll
      for (int i = 0; i < MH; i++) mfma2(ha, hb, i, j);
      readBf(hb * 2 + j, rbuf);
      __builtin_amdgcn_sched_group_barrier(0x8, MH * 2, 0);
      __builtin_amdgcn_sched_group_barrier(0x100, 2, 0);
    }
    __builtin_amdgcn_s_setprio(0);
  };

#define BAR() __builtin_amdgcn_s_barrier()
#define VMC(n) asm volatile("s_waitcnt vmcnt(%0)" ::"i"(n) : "memory")

  // prologue: lds0 <- tile0 (A,B); lds1 <- B(t1); allow lds1's B outstanding
  stageAu(0, 0, lds0); stageAu(0, 1, lds0);
  stageBu(0, 0, lds0); stageBu(0, 1, lds0);
  stageBu(1, 0, lds1); stageBu(1, 1, lds1);
  VMC(2 * LB); BAR();
#pragma unroll
  for (int i = 0; i < MH; i++) readAf(i, lds0, 0);   // A0(t0)
#pragma unroll
  for (int f = 0; f < 4; f++) readBf(f, lds0);       // B0,B1(t0)

  int jj = 0;
  auto run_iter = [&](auto more_c) {
    constexpr bool more = decltype(more_c)::value;
    const int t1 = 2 * jj + 1, t2 = t1 + 1, t3 = t1 + 2;
    // ph0: Q(0,0); stage Au0(t1)->lds1
    stageAu(t1, 0, lds1);
    clusterPlain(0, 0);
    BAR();
    // ph1: Q(0,1) + reload af<-lds0.A1(t0); stage Au1(t1)->lds1
    stageAu(t1, 1, lds1);
    clusterA_r(0, 1, lds0, 1);
    VMC(2 * LA); BAR();                 // forces B(t1) landed (for ph2 reads)
    // ph2: Q(1,0) + reload B-pair0<-lds1(t1); stage Bu0(t2)->lds0
    if constexpr (more) stageBu(t2, 0, lds0);
    clusterB_r(1, 0, lds1);
    VMC(more ? LB : 0); BAR();          // forces A(t1) landed (for ph3 reads)
    // ph3: Q(1,1) + reload af<-lds1.A0(t1); tail: B-pair1<-lds1; stage Bu1(t2)->lds0
    if constexpr (more) stageBu(t2, 1, lds0);
    clusterA_r(1, 1, lds1, 0);
    readBf(2, lds1); readBf(3, lds1);
    BAR();
    // ph4: Q(0,0) on t1 frags; stage Au0(t2)->lds0
    if constexpr (more) stageAu(t2, 0, lds0);
    clusterPlain(0, 0);
    BAR();
    // ph5: Q(0,1) + reload af<-lds1.A1(t1); stage Au1(t2)->lds0
    if constexpr (more) stageAu(t2, 1, lds0);
    clusterA_r(0, 1, lds1, 1);
    if constexpr (more) { VMC(2 * LA); }  // forces B(t2) (for ph6 reads)
    BAR();
    // ph6: Q(1,0) + reload B-pair0<-lds0(t2); stage Bu0(t3)->lds1
    if constexpr (more) {
      stageBu(t3, 0, lds1);
      clusterB_r(1, 0, lds0);
      VMC(LB);                          // forces A(t2) (for ph7 reads)
    } else {
      clusterPlain(1, 0);
    }
    BAR();
    // ph7: Q(1,1) + reload af<-lds0.A0(t2); tail B-pair1<-lds0; stage Bu1(t3)->lds1
    if constexpr (more) {
      stageBu(t3, 1, lds1);
      clusterA_r(1, 1, lds0, 0);
      readBf(2, lds0); readBf(3, lds0);
    } else {
      clusterPlain(1, 1);
    }
    BAR();
    jj++;
  };

  const int NT2 = K / 128;
  for (int j = 0; j < NT2 - 1; j++) run_iter(std::integral_constant<bool, true>{});
  run_iter(std::integral_constant<bool, false>{});

  // epilogue: C/D layout col = lane&15, row = (lane>>4)*4 + reg
  const int rbase = bm * BM + wm * (BM / 2) + lg * 4;
  const int cbase = bn * BN + wn * 64 + lr;
#pragma unroll
  for (int f = 0; f < MF; f++)
#pragma unroll
    for (int rr = 0; rr < 4; rr++) {
      size_t rowoff = (size_t)(rbase + f * 16 + rr) * N + cbase;
#pragma unroll
      for (int nf = 0; nf < NF; nf++) C[rowoff + nf * 16] = (CT)acc[f][nf][rr];
    }
#undef BAR
#undef VMC
}

// ---------------- q/k postprocess: RMS, RoPE, key-offset ----------------
__global__ __launch_bounds__(512) void k_qk(
    const __bf16* __restrict__ qkv, const float* __restrict__ f1,
    const float* __restrict__ f2, const int* __restrict__ koff_p,
    __bf16* __restrict__ qb, __bf16* __restrict__ kb) {
  const int t = blockIdx.x;
  const int h = threadIdx.x >> 6;
  const int l = threadIdx.x & 63;
  const int d0 = 2 * l;
  const size_t qoff = (size_t)t * (3 * DIMM) + h * HD;

  bfx2 qv = *(const bfx2*)&qkv[qoff + d0];
  bfx2 kv = *(const bfx2*)&qkv[qoff + DIMM + d0];
  float q0 = (float)qv[0], q1 = (float)qv[1];
  float k0 = (float)kv[0], k1 = (float)kv[1];

  float sq = q0 * q0 + q1 * q1;
  float sk = k0 * k0 + k1 * k1;
#pragma unroll
  for (int off = 32; off; off >>= 1) {
    sq += __shfl_xor(sq, off);
    sk += __shfl_xor(sk, off);
  }
  float rq = rsqrtf(sq * (1.0f / 128.0f) + RMS_EPS);
  float rk = rsqrtf(sk * (1.0f / 128.0f) + RMS_EPS);
  q0 *= rq; q1 *= rq; k0 *= rk; k1 *= rk;

  float2 cc = *(const float2*)&f1[(size_t)t * HD + d0];
  float2 ss = *(const float2*)&f2[(size_t)t * HD + d0];
  float rq0 = cc.x * q0 + ss.x * q1, rq1 = cc.y * q1 + ss.y * q0;
  float rk0 = cc.x * k0 + ss.x * k1, rk1 = cc.y * k1 + ss.y * k0;

  bfx2 qo; qo[0] = (__bf16)rq0; qo[1] = (__bf16)rq1;
  *(bfx2*)&qb[(size_t)t * DIMM + h * HD + d0] = qo;

  bfx2 ko2; ko2[0] = (__bf16)rk0; ko2[1] = (__bf16)rk1;
  const int koff = *koff_p;
  const size_t kcol = (size_t)h * HD + d0;
  if (!koff || l < 32) {
    *(bfx2*)&kb[(size_t)t * DIMM + kcol] = ko2;
  } else {
    if (t + 1 < TSEQ) *(bfx2*)&kb[(size_t)(t + 1) * DIMM + kcol] = ko2;
    if (t == 0)       *(bfx2*)&kb[kcol] = ko2;
  }
}

// ---------------- v postprocess: gates + ve-gate + LDS-tiled transpose ----------------
__global__ __launch_bounds__(512) void k_vgate(
    const __bf16* __restrict__ qkv, const float* __restrict__ x,
    const float* __restrict__ ve, const float* __restrict__ agw,
    const float* __restrict__ vgw, __bf16* __restrict__ vT,
    float* __restrict__ ag) {
  __shared__ float vg_lds[64][4];
  __shared__ __bf16 vtile[HD][68];
  const int t0 = blockIdx.x * 64;
  const int hbase = blockIdx.y * 4;
  const int tid = threadIdx.x;

  if (tid < 256) {
    const int tl = tid >> 2, hh = tid & 3;
    const int h = hbase + hh;
    const int t = t0 + tl;
    float za = 0.0f, zg = 0.0f;
#pragma unroll
    for (int j = 0; j < 12; j++) {
      float xv = x[(size_t)t * DIMM + j];
      za += xv * agw[h * 12 + j];
      zg += xv * vgw[h * 12 + j];
    }
    ag[(size_t)t * NHEAD + h] = sig_(za);
    vg_lds[tl][hh] = 2.0f * sig_(zg);
  }
  __syncthreads();

  const int w = tid >> 6, l = tid & 63;
  const int dout = tid >> 2, tof = (tid & 3) * 16;
  for (int hh = 0; hh < 4; hh++) {
    const int h = hbase + hh;
#pragma unroll
    for (int it = 0; it < 8; it++) {
      const int tl = w * 8 + it;
      const int t = t0 + tl;
      const size_t voff = (size_t)t * (3 * DIMM) + 2 * DIMM + h * HD;
      float va = (float)qkv[voff + l];
      float vb = (float)qkv[voff + l + 64];
      float vea = ve[(size_t)t * DIMM + h * HD + l];
      float veb = ve[(size_t)t * DIMM + h * HD + l + 64];
      float gv = vg_lds[tl][hh];
      vtile[l][tl]      = (__bf16)(va + gv * vea);
      vtile[l + 64][tl] = (__bf16)(vb + gv * veb);
    }
    __syncthreads();
    {
      bfx4 a0 = *(const bfx4*)&vtile[dout][tof];
      bfx4 a1 = *(const bfx4*)&vtile[dout][tof + 4];
      bfx4 a2 = *(const bfx4*)&vtile[dout][tof + 8];
      bfx4 a3 = *(const bfx4*)&vtile[dout][tof + 12];
      bfx8 p0, p1;
      p0[0]=a0[0]; p0[1]=a0[1]; p0[2]=a0[2]; p0[3]=a0[3];
      p0[4]=a1[0]; p0[5]=a1[1]; p0[6]=a1[2]; p0[7]=a1[3];
      p1[0]=a2[0]; p1[1]=a2[1]; p1[2]=a2[2]; p1[3]=a2[3];
      p1[4]=a3[0]; p1[5]=a3[1]; p1[6]=a3[2]; p1[7]=a3[3];
      __bf16* dst = &vT[(size_t)(h * HD + dout) * TSEQ + t0 + tof];
      *(bfx8*)dst = p0;
      *(bfx8*)(dst + 8) = p1;
    }
    __syncthreads();
  }
}

// ---------------- windowed varlen flash attention, S^T single-pass ----------------
__global__ __launch_bounds__(256, 4) void k_attn2(
    const __bf16* __restrict__ qb, const __bf16* __restrict__ kb,
    const __bf16* __restrict__ vT, const float* __restrict__ ag,
    const int* __restrict__ sl, int ns, __bf16* __restrict__ yb) {
  const int h = blockIdx.y;
  const int w = threadIdx.x >> 6, l = threadIdx.x & 63;
  const int lr = l & 15, lg = l >> 4;
  const int q0r = (blockIdx.x * 4 + w) * 16;
  const int kbase = q0r - 128;
  const int q = q0r + lr;
  const int kfs = (q0r < 128) ? ((128 - q0r) >> 4) : 0;

  bfx8 qf[4];
#pragma unroll
  for (int ds = 0; ds < 4; ds++)
    qf[ds] = *(const bfx8*)&qb[(size_t)q * DIMM + h * HD + ds * 32 + lg * 8];

  int segs = 0;
  for (int i = 0; i < ns; i++) {
    int v = sl[i];
    segs = (v <= q) ? ((v > segs) ? v : segs) : segs;
  }
  int klo = q - 128;
  if (segs > klo) klo = segs;
  if (klo < 0) klo = 0;

  f32x4 sf[9] = {};
#pragma unroll
  for (int kf = 0; kf < 9; kf++) {
    if (kf >= kfs) {
      const int krow = kbase + kf * 16 + lr;
      const __bf16* kp = &kb[(size_t)krow * DIMM + h * HD + lg * 8];
      bfx8 k0 = *(const bfx8*)(kp);
      bfx8 k1 = *(const bfx8*)(kp + 32);
      bfx8 k2 = *(const bfx8*)(kp + 64);
      bfx8 k3 = *(const bfx8*)(kp + 96);
      sf[kf] = __builtin_amdgcn_mfma_f32_16x16x32_bf16(k0, qf[0], sf[kf], 0, 0, 0);
      sf[kf] = __builtin_amdgcn_mfma_f32_16x16x32_bf16(k1, qf[1], sf[kf], 0, 0, 0);
      sf[kf] = __builtin_amdgcn_mfma_f32_16x16x32_bf16(k2, qf[2], sf[kf], 0, 0, 0);
      sf[kf] = __builtin_amdgcn_mfma_f32_16x16x32_bf16(k3, qf[3], sf[kf], 0, 0, 0);
    }
  }

#pragma unroll
  for (int kf = 0; kf < 9; kf++)
#pragma unroll
    for (int rr = 0; rr < 4; rr++) {
      int k = kbase + kf * 16 + lg * 4 + rr;
      bool valid = (k >= klo) && (k <= q);
      sf[kf][rr] = valid ? sf[kf][rr] * ATTN_SCALE : -1e30f;
    }

  float mx = -1e30f;
#pragma unroll
  for (int kf = 0; kf < 9; kf++)
#pragma unroll
    for (int rr = 0; rr < 4; rr++) mx = fmaxf(mx, sf[kf][rr]);
  mx = fmaxf(mx, __shfl_xor(mx, 16));
  mx = fmaxf(mx, __shfl_xor(mx, 32));

  float lsum = 0.0f;
#pragma unroll
  for (int kf = 0; kf < 9; kf++)
#pragma unroll
    for (int rr = 0; rr < 4; rr++) {
      float p = __expf(sf[kf][rr] - mx);
      sf[kf][rr] = p;
      lsum += p;
    }
  lsum += __shfl_xor(lsum, 16);
  lsum += __shfl_xor(lsum, 32);

  f32x4 o[8] = {};
#pragma unroll
  for (int kf = 0; kf < 9; kf++) {
    if (kf >= kfs) {
      bfx4 pc;
      pc[0] = (__bf16)sf[kf][0]; pc[1] = (__bf16)sf[kf][1];
      pc[2] = (__bf16)sf[kf][2]; pc[3] = (__bf16)sf[kf][3];
      s16x4 pb = *(s16x4*)&pc;
      const int kk = kbase + kf * 16 + 4 * lg;
#pragma unroll
      for (int nf = 0; nf < 8; nf++) {
        s16x4 vf = *(const s16x4*)&vT[(size_t)(h * HD + nf * 16 + lr) * TSEQ + kk];
        o[nf] = __builtin_amdgcn_mfma_f32_16x16x16bf16_1k(vf, pb, o[nf], 0, 0, 0);
      }
    }
  }

  const float sc = ag[(size_t)q * NHEAD + h] / lsum;
#pragma unroll
  for (int nf = 0; nf < 8; nf++) {
    bfx4 st;
#pragma unroll
    for (int rr = 0; rr < 4; rr++) st[rr] = (__bf16)(o[nf][rr] * sc);
    *(bfx4*)&yb[(size_t)q * DIMM + h * HD + nf * 16 + lg * 4] = st;
  }
}

// ---------------- launch ----------------
extern "C" void kernel_launch(void* const* d_in, const int* in_sizes, int n_in,
                              void* d_out, int out_size, void* d_ws, size_t ws_size,
                              hipStream_t stream) {
  const float* x   = (const float*)d_in[0];
  const float* qw  = (const float*)d_in[1];
  const float* ve  = (const float*)d_in[2];
  const float* lam = (const float*)d_in[3];
  const float* f1  = (const float*)d_in[4];
  const float* f2  = (const float*)d_in[5];
  const float* agw = (const float*)d_in[6];
  const float* vgw = (const float*)d_in[7];
  const int*   sl  = (const int*)d_in[8];
  const int    ns  = in_sizes[8];
  const int*   koff = (const int*)d_in[10];
  float* out = (float*)d_out;
  char* ws = (char*)d_ws;

  const size_t MB = 1024 * 1024;
  if (ws_size < 105 * MB) return;
  __bf16* xb   = (__bf16*)(ws);
  __bf16* w1b  = (__bf16*)(ws + 16 * MB);
  __bf16* w2b  = (__bf16*)(ws + 22 * MB);
  __bf16* qkvb = (__bf16*)(ws + 24 * MB);
  __bf16* qbuf = (__bf16*)(ws + 72 * MB);
  __bf16* kbuf = (__bf16*)(ws + 88 * MB);
  float*  ag   = (float*)(ws + 104 * MB);
  __bf16* vT   = xb;    // xb dead after GEMM1
  __bf16* ybuf = qkvb;  // qkvb dead after k_qk/k_vgate

  k_conv_x<<<2048, 256, 0, stream>>>((const float4*)x, (bfx4*)xb, TSEQ * DIMM / 4);
  k_conv_w<<<1024, 256, 0, stream>>>((const float4*)qw, lam, (bfx4*)w1b, (bfx4*)w2b);
  k_gemm8i<128, __bf16><<<dim3(TSEQ / 128, 3 * DIMM / 256), 512, 0, stream>>>(
      xb, w1b, qkvb, TSEQ, 3 * DIMM, DIMM);
  k_qk<<<TSEQ, 512, 0, stream>>>(qkvb, f1, f2, koff, qbuf, kbuf);
  k_vgate<<<dim3(TSEQ / 64, 2), 512, 0, stream>>>(qkvb, x, ve, agw, vgw, vT, ag);
  k_attn2<<<dim3(TSEQ / 64, NHEAD), 256, 0, stream>>>(qbuf, kbuf, vT, ag, sl, ns, ybuf);
  k_gemm8i<128, float><<<dim3(TSEQ / 128, DIMM / 256), 512, 0, stream>>>(
      ybuf, w2b, out, TSEQ, DIMM, DIMM);
}